// Round 4
// baseline (363.676 us; speedup 1.0000x reference)
//
#include <hip/hip_runtime.h>
#include <stdint.h>

// E=512, H=8, D=64, B=4, Nq=Nk=2048
// bf16 MFMA pipeline: cvt -> QKV proj GEMM (Q pre-scaled) -> flash attn
// (masked via MFMA C-in, KV-split x4 per block, bh->XCD locality swizzle,
//  LDS combine) -> out proj GEMM

typedef __attribute__((ext_vector_type(8))) short bf16x8;  // 8 bf16 in 4 VGPRs
typedef __attribute__((ext_vector_type(4))) float f32x4;

#define SCLQ 0.18033688011112042f  // 0.125 * log2(e): logits emerge in log2 domain

static __device__ __forceinline__ unsigned short f2bf(float f) {
    union { float f; unsigned u; } x; x.f = f;
    unsigned r = x.u + 0x7fffu + ((x.u >> 16) & 1u);  // RTN-even
    return (unsigned short)(r >> 16);
}

static __device__ __forceinline__ f32x4 mfma16(bf16x8 a, bf16x8 b, f32x4 c) {
    return __builtin_amdgcn_mfma_f32_16x16x32_bf16(a, b, c, 0, 0, 0);
}

#define GLOAD_LDS16(g, l)                                                            \
    __builtin_amdgcn_global_load_lds((const __attribute__((address_space(1))) void*)(g), \
                                     (__attribute__((address_space(3))) void*)(l), 16, 0, 0)

// ---------------- conversion kernels ----------------

__global__ __launch_bounds__(256) void cvt_x_kernel(
    const float* __restrict__ xq, const float* __restrict__ xk, const float* __restrict__ xv,
    short* __restrict__ oq, short* __restrict__ ok, short* __restrict__ ov)
{
    const float* src = (blockIdx.y == 0) ? xq : (blockIdx.y == 1) ? xk : xv;
    short* dst = (blockIdx.y == 0) ? oq : (blockIdx.y == 1) ? ok : ov;
    size_t i = (size_t)blockIdx.x * 256 + threadIdx.x;
    float4 v = ((const float4*)src)[i];
    short4 o;
    o.x = (short)f2bf(v.x); o.y = (short)f2bf(v.y);
    o.z = (short)f2bf(v.z); o.w = (short)f2bf(v.w);
    ((short4*)dst)[i] = o;
}

__global__ __launch_bounds__(256) void cvt_wt_kernel(
    const float* __restrict__ Wq, const float* __restrict__ Wk,
    const float* __restrict__ Wv, const float* __restrict__ Wo,
    short* __restrict__ WqT, short* __restrict__ WkT,
    short* __restrict__ WvT, short* __restrict__ WoT)
{
    int z = blockIdx.y;
    const float* W = (z == 0) ? Wq : (z == 1) ? Wk : (z == 2) ? Wv : Wo;
    short* WT = (z == 0) ? WqT : (z == 1) ? WkT : (z == 2) ? WvT : WoT;
    int t = blockIdx.x * 256 + threadIdx.x;
    int n = t & 511;
    int k0 = (t >> 9) * 8;
    union { short s[8]; int4 v; } u;
#pragma unroll
    for (int j = 0; j < 8; ++j) u.s[j] = (short)f2bf(W[(size_t)(k0 + j) * 512 + n]);
    *(int4*)(WT + (size_t)n * 512 + k0) = u.v;
}

// mask (4-byte elems, nonzero = keep) -> packed bits; word w covers k=[w*64,w*64+64)
__global__ __launch_bounds__(256) void pack_mask_kernel(
    const int* __restrict__ mask, unsigned long long* __restrict__ mp)
{
    int lane = threadIdx.x & 63;
    int row = blockIdx.x * 4 + (threadIdx.x >> 6);  // b*2048+q
    const int* mrow = mask + (size_t)row * 2048;
#pragma unroll 4
    for (int w = 0; w < 32; ++w) {
        unsigned long long bits = __ballot(mrow[w * 64 + lane] != 0);
        if (lane == 0) mp[(size_t)row * 32 + w] = bits;
    }
}

// ---------------- GEMM: C[8192x512] = A[8192x512] @ W  (+bias) ----------------
// mode 0: Q -> [b,h,tok,d] bf16, pre-scaled by 0.125*log2e ; 1: K -> [b,h,tok,d]
// mode 2: V -> [b,h,d,tok] bf16 ; 3: fp32 row-major out
__global__ __launch_bounds__(256) void gemm_kernel(
    const short* __restrict__ A, const short* __restrict__ BT,
    const float* __restrict__ bias, void* __restrict__ Cout, int mode)
{
    __shared__ char lds[32768];
    const int tid = threadIdx.x;
    const int lane = tid & 63;
    const int wid = tid >> 6;
    const int l15 = lane & 15, l4 = lane >> 4;
    const int m0 = blockIdx.y * 128;
    const int n0 = blockIdx.x * 128;
    const int wr = wid >> 1, wc = wid & 1;

    f32x4 zero = {0.f, 0.f, 0.f, 0.f};
    f32x4 acc[4][4];
#pragma unroll
    for (int i = 0; i < 4; ++i)
#pragma unroll
        for (int j = 0; j < 4; ++j) acc[i][j] = zero;

    char* Alds = lds;
    char* Blds = lds + 16384;

    for (int t = 0; t < 8; ++t) {
        const int k0 = t * 64;
#pragma unroll
        for (int s = 0; s < 4; ++s) {
            int p = s * 256 + tid;
            int r = p >> 3, c = p & 7;
            GLOAD_LDS16(A + (size_t)(m0 + r) * 512 + k0 + 8 * (c ^ (r & 7)),
                        Alds + s * 4096 + wid * 1024);
            GLOAD_LDS16(BT + (size_t)(n0 + r) * 512 + k0 + 8 * (c ^ (r & 7)),
                        Blds + s * 4096 + wid * 1024);
        }
        __syncthreads();
#pragma unroll
        for (int ks = 0; ks < 2; ++ks) {
            bf16x8 af[4], bfr[4];
#pragma unroll
            for (int mb = 0; mb < 4; ++mb) {
                int row = wr * 64 + mb * 16 + l15;
                af[mb] = *(const bf16x8*)(Alds + row * 128 +
                                          ((ks * 64 + l4 * 16) ^ ((row & 7) << 4)));
            }
#pragma unroll
            for (int nb = 0; nb < 4; ++nb) {
                int row = wc * 64 + nb * 16 + l15;
                bfr[nb] = *(const bf16x8*)(Blds + row * 128 +
                                           ((ks * 64 + l4 * 16) ^ ((row & 7) << 4)));
            }
#pragma unroll
            for (int mb = 0; mb < 4; ++mb)
#pragma unroll
                for (int nb = 0; nb < 4; ++nb)
                    acc[mb][nb] = mfma16(af[mb], bfr[nb], acc[mb][nb]);
        }
        __syncthreads();
    }

#pragma unroll
    for (int nb = 0; nb < 4; ++nb) {
        int n = n0 + wc * 64 + nb * 16 + l15;
        float bv = bias[n];
#pragma unroll
        for (int mb = 0; mb < 4; ++mb) {
#pragma unroll
            for (int r = 0; r < 4; ++r) {
                int m = m0 + wr * 64 + mb * 16 + l4 * 4 + r;
                float val = acc[mb][nb][r] + bv;
                if (mode == 0) val *= SCLQ;  // fold softmax scale+log2e into Q
                if (mode == 3) {
                    ((float*)Cout)[(size_t)m * 512 + n] = val;
                } else {
                    int b = m >> 11, tok = m & 2047;
                    int h = n >> 6, d = n & 63;
                    short* o = (short*)Cout;
                    if (mode == 2)
                        o[((size_t)(b * 8 + h) * 64 + d) * 2048 + tok] = (short)f2bf(val);
                    else
                        o[((size_t)(b * 8 + h) * 2048 + tok) * 64 + d] = (short)f2bf(val);
                }
            }
        }
    }
}

// ---------------- masked flash attention (KV-split x4, bh->XCD pinning) ----------------
// 1-D grid of 2048. HW round-robins dispatch ids over 8 XCDs, so decode
// xcd = lid&7 and pin bh = xcd*4 + ((lid>>3)>>6): each XCD serves exactly 4 (b,h),
// keeping that bh's K/V (512 KB) L2-resident across its 64 q-blocks.
// Block owns 32 q-rows; wave w handles kv-tiles [w*8, w*8+8). Swapped QK^T
// (S^T: col=l15=q, row=l4*4+r=k); mask applied as MFMA C-init (0/-1e30);
// Q pre-scaled so logits are log2-domain. Partials (m,l,O) combined via LDS.
__global__ __launch_bounds__(256, 4) void attn_kernel(
    const short* __restrict__ Q, const short* __restrict__ K,
    const short* __restrict__ VT, const unsigned long long* __restrict__ mp,
    short* __restrict__ AO)
{
    // LDS map: [0,16384): per-wave P buffers (phase 1, wid*4096)
    //          [0,33280): Of partials f32, stride 260 B/row (phase 2, overlaps P)
    //          [33280,34304): (m,l) float2 per (wave, q)
    __shared__ char lds[34304];
    const int lane = threadIdx.x & 63;
    const int wid = threadIdx.x >> 6;
    const int l15 = lane & 15, l4 = lane >> 4;
    // bh->XCD locality decode (bijective over 2048 blocks)
    const int lid = blockIdx.x;
    const int xcd = lid & 7, j = lid >> 3;
    const int bhi = (xcd << 2) | (j >> 6);
    const int b = bhi >> 3, h = bhi & 7;
    const int q0 = (j & 63) * 32;
    const size_t bh = (size_t)b * 8 + h;
    const short* Qp = Q + (bh * 2048 + q0) * 64;
    const short* Kp = K + (bh * 2048 + (size_t)wid * 512) * 64;  // wave's kv quarter
    const short* Vp = VT + bh * 64 * 2048;
    const int ktb = wid * 8;
    char* Pw = lds + wid * 4096;
    const int sw = (l15 & 7) << 4;  // per-row XOR swizzle (G4)

    // Q fragments (persistent): aq[qs][ds] = Q[q0+qs*16+l15][ds*32 + l4*8 + j]
    bf16x8 aq[2][2];
#pragma unroll
    for (int qs = 0; qs < 2; ++qs)
#pragma unroll
        for (int ds = 0; ds < 2; ++ds)
            aq[qs][ds] = *(const bf16x8*)(Qp + (qs * 16 + l15) * 64 + ds * 32 + l4 * 8);

    const f32x4 zero = {0.f, 0.f, 0.f, 0.f};
    f32x4 o[2][4];
    float mrun[2] = {-1e30f, -1e30f}, lrun[2] = {0.f, 0.f};
#pragma unroll
    for (int qs = 0; qs < 2; ++qs)
#pragma unroll
        for (int dt = 0; dt < 4; ++dt) o[qs][dt] = zero;

    const unsigned long long* mr0 = mp + ((size_t)b * 2048 + q0 + l15) * 32 + ktb;
    const unsigned long long* mr1 = mr0 + 16 * 32;

    // single-buffered K/V frags; prefetch issued after last consumer (WAR, in-order)
    bf16x8 kf[4][2], vf[4][2];
#pragma unroll
    for (int kb = 0; kb < 4; ++kb)
#pragma unroll
        for (int ds = 0; ds < 2; ++ds)
            kf[kb][ds] = *(const bf16x8*)(Kp + (kb * 16 + l15) * 64 + ds * 32 + l4 * 8);
#pragma unroll
    for (int dt = 0; dt < 4; ++dt)
#pragma unroll
        for (int ks = 0; ks < 2; ++ks)
            vf[dt][ks] = *(const bf16x8*)(Vp + (size_t)(dt * 16 + l15) * 2048 +
                                          ktb * 64 + ks * 32 + l4 * 8);
    unsigned long long mwq0 = mr0[0], mwq1 = mr1[0];
    unsigned long long mwn0 = 0, mwn1 = 0;

// QK^T with mask as C-init: sv[kb] = K*Q + (bit ? 0 : -1e30)
#define QKT_BLOCK(QS, MWQ)                                                        \
    {                                                                             \
        unsigned long long ms_ = (MWQ) >> (l4 * 4);                               \
        unsigned w0_ = (unsigned)ms_, w1_ = (unsigned)(ms_ >> 32);                \
        _Pragma("unroll") for (int kb = 0; kb < 4; ++kb) {                        \
            unsigned ws_ = (kb & 2) ? w1_ : w0_;                                  \
            f32x4 ini;                                                            \
            _Pragma("unroll") for (int r = 0; r < 4; ++r)                         \
                ini[r] = (ws_ & (1u << (((kb & 1) << 4) + r))) ? 0.f : -1e30f;    \
            sv[kb] = mfma16(kf[kb][1], aq[QS][1],                                 \
                            mfma16(kf[kb][0], aq[QS][0], ini));                   \
        }                                                                         \
    }

// tree max -> 2 shfl -> defer-max rescale -> exp2 -> pack -> swizzled P write
#define SM_BLOCK(QS)                                                              \
    {                                                                             \
        float pk0 = fmaxf(fmaxf(sv[0][0], sv[0][1]), fmaxf(sv[0][2], sv[0][3]));  \
        float pk1 = fmaxf(fmaxf(sv[1][0], sv[1][1]), fmaxf(sv[1][2], sv[1][3]));  \
        float pk2 = fmaxf(fmaxf(sv[2][0], sv[2][1]), fmaxf(sv[2][2], sv[2][3]));  \
        float pk3 = fmaxf(fmaxf(sv[3][0], sv[3][1]), fmaxf(sv[3][2], sv[3][3]));  \
        float pm = fmaxf(fmaxf(pk0, pk1), fmaxf(pk2, pk3));                       \
        pm = fmaxf(pm, __shfl_xor(pm, 16, 64));                                   \
        pm = fmaxf(pm, __shfl_xor(pm, 32, 64));                                   \
        if (__any(pm > mrun[QS] + 8.f)) {                                         \
            float mnew = fmaxf(mrun[QS], pm);                                     \
            float al = exp2f(mrun[QS] - mnew);                                    \
            mrun[QS] = mnew; lrun[QS] *= al;                                      \
            _Pragma("unroll") for (int r = 0; r < 4; ++r) {                       \
                float aR = __shfl(al, l4 * 4 + r, 64);                            \
                _Pragma("unroll") for (int dt = 0; dt < 4; ++dt)                  \
                    o[QS][dt][r] *= aR;                                           \
            }                                                                     \
        }                                                                         \
        float sk0, sk1, sk2, sk3;                                                 \
        _Pragma("unroll") for (int kb = 0; kb < 4; ++kb) {                        \
            float e0 = exp2f(sv[kb][0] - mrun[QS]);                               \
            float e1 = exp2f(sv[kb][1] - mrun[QS]);                               \
            float e2 = exp2f(sv[kb][2] - mrun[QS]);                               \
            float e3 = exp2f(sv[kb][3] - mrun[QS]);                               \
            float sk_ = (e0 + e1) + (e2 + e3);                                    \
            if (kb == 0) sk0 = sk_; else if (kb == 1) sk1 = sk_;                  \
            else if (kb == 2) sk2 = sk_; else sk3 = sk_;                          \
            unsigned u0, u1;                                                      \
            asm("v_cvt_pk_bf16_f32 %0, %1, %2" : "=v"(u0) : "v"(e0), "v"(e1));    \
            asm("v_cvt_pk_bf16_f32 %0, %1, %2" : "=v"(u1) : "v"(e2), "v"(e3));    \
            uint2 wv; wv.x = u0; wv.y = u1;                                       \
            *(uint2*)(Pw + (QS) * 2048 + l15 * 128 + ((kb * 32 + l4 * 8) ^ sw)) = wv; \
        }                                                                         \
        float ls = (sk0 + sk1) + (sk2 + sk3);                                     \
        ls += __shfl_xor(ls, 16, 64);                                             \
        ls += __shfl_xor(ls, 32, 64);                                             \
        lrun[QS] += ls;                                                           \
    }

#pragma unroll
    for (int lt = 0; lt < 8; ++lt) {
        f32x4 sv[4];
        QKT_BLOCK(0, mwq0)
        SM_BLOCK(0)
        QKT_BLOCK(1, mwq1)
        if (lt < 7) {  // K+mask prefetch for lt+1 (kf fully consumed above)
#pragma unroll
            for (int kb = 0; kb < 4; ++kb)
#pragma unroll
                for (int ds = 0; ds < 2; ++ds)
                    kf[kb][ds] = *(const bf16x8*)(Kp + ((lt + 1) * 64 + kb * 16 + l15) * 64 +
                                                  ds * 32 + l4 * 8);
            mwn0 = mr0[lt + 1]; mwn1 = mr1[lt + 1];
        }
        SM_BLOCK(1)
        asm volatile("s_waitcnt lgkmcnt(0)" ::: "memory");  // P writes visible to own wave
        // PV: A = P[q=l15][k contiguous], B = vf (col=l15=d)
#pragma unroll
        for (int qs = 0; qs < 2; ++qs)
#pragma unroll
            for (int ks = 0; ks < 2; ++ks) {
                bf16x8 ap = *(const bf16x8*)(Pw + qs * 2048 + l15 * 128 +
                                             ((ks * 64 + l4 * 16) ^ sw));
#pragma unroll
                for (int dt = 0; dt < 4; ++dt)
                    o[qs][dt] = mfma16(ap, vf[dt][ks], o[qs][dt]);
            }
        if (lt < 7) {  // V prefetch for lt+1 (vf fully consumed by PV above)
#pragma unroll
            for (int dt = 0; dt < 4; ++dt)
#pragma unroll
                for (int ks = 0; ks < 2; ++ks)
                    vf[dt][ks] = *(const bf16x8*)(Vp + (size_t)(dt * 16 + l15) * 2048 +
                                                  (ktb + lt + 1) * 64 + ks * 32 + l4 * 8);
            mwq0 = mwn0; mwq1 = mwn1;
        }
    }
#undef QKT_BLOCK
#undef SM_BLOCK

    // ---- combine the 4 kv-quarter partials through LDS ----
    __syncthreads();  // P buffers dead everywhere; Of region may now overwrite them
#pragma unroll
    for (int qs = 0; qs < 2; ++qs) {
#pragma unroll
        for (int dt = 0; dt < 4; ++dt)
#pragma unroll
            for (int r = 0; r < 4; ++r)
                *(float*)(lds + wid * 8320 + (qs * 16 + l4 * 4 + r) * 260 +
                          (dt * 16 + l15) * 4) = o[qs][dt][r];
        if (l4 == 0) {
            float2 v; v.x = mrun[qs]; v.y = lrun[qs];
            *(float2*)(lds + 33280 + (wid * 32 + qs * 16 + l15) * 8) = v;
        }
    }
    __syncthreads();
    {
        int q = threadIdx.x >> 3;
        int d0 = (threadIdx.x & 7) * 8;
        float mW[4], lW[4];
#pragma unroll
        for (int w = 0; w < 4; ++w) {
            float2 v = *(const float2*)(lds + 33280 + (w * 32 + q) * 8);
            mW[w] = v.x; lW[w] = v.y;
        }
        float m = fmaxf(fmaxf(mW[0], mW[1]), fmaxf(mW[2], mW[3]));
        float wg[4]; float lsum = 0.f;
#pragma unroll
        for (int w = 0; w < 4; ++w) { wg[w] = exp2f(mW[w] - m); lsum += lW[w] * wg[w]; }
        float inv = 1.0f / lsum;
        union { short s[8]; int4 v; } ou;
#pragma unroll
        for (int j = 0; j < 8; ++j) {
            float acc = 0.f;
#pragma unroll
            for (int w = 0; w < 4; ++w)
                acc += wg[w] * *(const float*)(lds + w * 8320 + q * 260 + (d0 + j) * 4);
            ou.s[j] = (short)f2bf(acc * inv);
        }
        *(int4*)(AO + ((size_t)b * 2048 + q0 + q) * 512 + h * 64 + d0) = ou.v;
    }
}

// ---------------- launcher ----------------
extern "C" void kernel_launch(void* const* d_in, const int* in_sizes, int n_in,
                              void* d_out, int out_size, void* d_ws, size_t ws_size,
                              hipStream_t stream) {
    const float* q  = (const float*)d_in[0];
    const float* k  = (const float*)d_in[1];
    const float* v  = (const float*)d_in[2];
    const int*   gm = (const int*)d_in[3];
    const float* Wq = (const float*)d_in[4];  const float* bq = (const float*)d_in[5];
    const float* Wk = (const float*)d_in[6];  const float* bk = (const float*)d_in[7];
    const float* Wv = (const float*)d_in[8];  const float* bv = (const float*)d_in[9];
    const float* Wo = (const float*)d_in[10]; const float* bo = (const float*)d_in[11];

    char* ws = (char*)d_ws;
    short* Xq  = (short*)(ws + 0);
    short* Xk  = (short*)(ws + 8388608);
    short* Xv  = (short*)(ws + 16777216);
    short* WqT = (short*)(ws + 25165824);
    short* WkT = (short*)(ws + 25690112);
    short* WvT = (short*)(ws + 26214400);
    short* WoT = (short*)(ws + 26738688);
    short* Qw  = (short*)(ws + 27262976);    // [b,h,tok,d] (pre-scaled)
    short* Kw  = (short*)(ws + 35651584);    // [b,h,tok,d]
    short* VTw = (short*)(ws + 44040192);    // [b,h,d,tok]
    short* AO  = (short*)(ws + 52428800);    // attn out [b,tok,h*64+d]
    unsigned long long* MP = (unsigned long long*)(ws + 60817408);

    cvt_x_kernel<<<dim3(4096, 3), 256, 0, stream>>>(q, k, v, Xq, Xk, Xv);
    cvt_wt_kernel<<<dim3(128, 4), 256, 0, stream>>>(Wq, Wk, Wv, Wo, WqT, WkT, WvT, WoT);
    pack_mask_kernel<<<dim3(2048), 256, 0, stream>>>(gm, MP);

    gemm_kernel<<<dim3(4, 64), 256, 0, stream>>>(Xq, WqT, bq, Qw, 0);
    gemm_kernel<<<dim3(4, 64), 256, 0, stream>>>(Xk, WkT, bk, Kw, 1);
    gemm_kernel<<<dim3(4, 64), 256, 0, stream>>>(Xv, WvT, bv, VTw, 2);

    attn_kernel<<<dim3(2048), 256, 0, stream>>>(Qw, Kw, VTw, MP, AO);

    gemm_kernel<<<dim3(4, 64), 256, 0, stream>>>(AO, WoT, bo, (void*)d_out, 3);
}

// Round 5
// 243.739 us; speedup vs baseline: 1.4921x; 1.4921x over previous
//
#include <hip/hip_runtime.h>
#include <stdint.h>

// E=512, H=8, D=64, B=4, Nq=Nk=2048
// bf16 MFMA pipeline: cvt -> QKV proj GEMM (Q pre-scaled) -> flash attn
// (masked via MFMA C-in, KV-split x4 per block, bh->XCD pinning, slim-LDS
//  two-phase combine) -> out proj GEMM

typedef __attribute__((ext_vector_type(8))) short bf16x8;  // 8 bf16 in 4 VGPRs
typedef __attribute__((ext_vector_type(4))) float f32x4;

#define SCLQ 0.18033688011112042f  // 0.125 * log2(e): logits emerge in log2 domain

static __device__ __forceinline__ unsigned short f2bf(float f) {
    union { float f; unsigned u; } x; x.f = f;
    unsigned r = x.u + 0x7fffu + ((x.u >> 16) & 1u);  // RTN-even
    return (unsigned short)(r >> 16);
}

static __device__ __forceinline__ f32x4 mfma16(bf16x8 a, bf16x8 b, f32x4 c) {
    return __builtin_amdgcn_mfma_f32_16x16x32_bf16(a, b, c, 0, 0, 0);
}

#define GLOAD_LDS16(g, l)                                                            \
    __builtin_amdgcn_global_load_lds((const __attribute__((address_space(1))) void*)(g), \
                                     (__attribute__((address_space(3))) void*)(l), 16, 0, 0)

// ---------------- conversion kernels ----------------

__global__ __launch_bounds__(256) void cvt_x_kernel(
    const float* __restrict__ xq, const float* __restrict__ xk, const float* __restrict__ xv,
    short* __restrict__ oq, short* __restrict__ ok, short* __restrict__ ov)
{
    const float* src = (blockIdx.y == 0) ? xq : (blockIdx.y == 1) ? xk : xv;
    short* dst = (blockIdx.y == 0) ? oq : (blockIdx.y == 1) ? ok : ov;
    size_t i = (size_t)blockIdx.x * 256 + threadIdx.x;
    float4 v = ((const float4*)src)[i];
    short4 o;
    o.x = (short)f2bf(v.x); o.y = (short)f2bf(v.y);
    o.z = (short)f2bf(v.z); o.w = (short)f2bf(v.w);
    ((short4*)dst)[i] = o;
}

__global__ __launch_bounds__(256) void cvt_wt_kernel(
    const float* __restrict__ Wq, const float* __restrict__ Wk,
    const float* __restrict__ Wv, const float* __restrict__ Wo,
    short* __restrict__ WqT, short* __restrict__ WkT,
    short* __restrict__ WvT, short* __restrict__ WoT)
{
    int z = blockIdx.y;
    const float* W = (z == 0) ? Wq : (z == 1) ? Wk : (z == 2) ? Wv : Wo;
    short* WT = (z == 0) ? WqT : (z == 1) ? WkT : (z == 2) ? WvT : WoT;
    int t = blockIdx.x * 256 + threadIdx.x;
    int n = t & 511;
    int k0 = (t >> 9) * 8;
    union { short s[8]; int4 v; } u;
#pragma unroll
    for (int j = 0; j < 8; ++j) u.s[j] = (short)f2bf(W[(size_t)(k0 + j) * 512 + n]);
    *(int4*)(WT + (size_t)n * 512 + k0) = u.v;
}

// mask (4-byte elems, nonzero = keep) -> packed bits; word w covers k=[w*64,w*64+64)
__global__ __launch_bounds__(256) void pack_mask_kernel(
    const int* __restrict__ mask, unsigned long long* __restrict__ mp)
{
    int lane = threadIdx.x & 63;
    int row = blockIdx.x * 4 + (threadIdx.x >> 6);  // b*2048+q
    const int* mrow = mask + (size_t)row * 2048;
#pragma unroll 4
    for (int w = 0; w < 32; ++w) {
        unsigned long long bits = __ballot(mrow[w * 64 + lane] != 0);
        if (lane == 0) mp[(size_t)row * 32 + w] = bits;
    }
}

// ---------------- GEMM: C[8192x512] = A[8192x512] @ W  (+bias) ----------------
// mode 0: Q -> [b,h,tok,d] bf16, pre-scaled by 0.125*log2e ; 1: K -> [b,h,tok,d]
// mode 2: V -> [b,h,d,tok] bf16 ; 3: fp32 row-major out
__global__ __launch_bounds__(256) void gemm_kernel(
    const short* __restrict__ A, const short* __restrict__ BT,
    const float* __restrict__ bias, void* __restrict__ Cout, int mode)
{
    __shared__ char lds[32768];
    const int tid = threadIdx.x;
    const int lane = tid & 63;
    const int wid = tid >> 6;
    const int l15 = lane & 15, l4 = lane >> 4;
    const int m0 = blockIdx.y * 128;
    const int n0 = blockIdx.x * 128;
    const int wr = wid >> 1, wc = wid & 1;

    f32x4 zero = {0.f, 0.f, 0.f, 0.f};
    f32x4 acc[4][4];
#pragma unroll
    for (int i = 0; i < 4; ++i)
#pragma unroll
        for (int j = 0; j < 4; ++j) acc[i][j] = zero;

    char* Alds = lds;
    char* Blds = lds + 16384;

    for (int t = 0; t < 8; ++t) {
        const int k0 = t * 64;
#pragma unroll
        for (int s = 0; s < 4; ++s) {
            int p = s * 256 + tid;
            int r = p >> 3, c = p & 7;
            GLOAD_LDS16(A + (size_t)(m0 + r) * 512 + k0 + 8 * (c ^ (r & 7)),
                        Alds + s * 4096 + wid * 1024);
            GLOAD_LDS16(BT + (size_t)(n0 + r) * 512 + k0 + 8 * (c ^ (r & 7)),
                        Blds + s * 4096 + wid * 1024);
        }
        __syncthreads();
#pragma unroll
        for (int ks = 0; ks < 2; ++ks) {
            bf16x8 af[4], bfr[4];
#pragma unroll
            for (int mb = 0; mb < 4; ++mb) {
                int row = wr * 64 + mb * 16 + l15;
                af[mb] = *(const bf16x8*)(Alds + row * 128 +
                                          ((ks * 64 + l4 * 16) ^ ((row & 7) << 4)));
            }
#pragma unroll
            for (int nb = 0; nb < 4; ++nb) {
                int row = wc * 64 + nb * 16 + l15;
                bfr[nb] = *(const bf16x8*)(Blds + row * 128 +
                                           ((ks * 64 + l4 * 16) ^ ((row & 7) << 4)));
            }
#pragma unroll
            for (int mb = 0; mb < 4; ++mb)
#pragma unroll
                for (int nb = 0; nb < 4; ++nb)
                    acc[mb][nb] = mfma16(af[mb], bfr[nb], acc[mb][nb]);
        }
        __syncthreads();
    }

#pragma unroll
    for (int nb = 0; nb < 4; ++nb) {
        int n = n0 + wc * 64 + nb * 16 + l15;
        float bv = bias[n];
#pragma unroll
        for (int mb = 0; mb < 4; ++mb) {
#pragma unroll
            for (int r = 0; r < 4; ++r) {
                int m = m0 + wr * 64 + mb * 16 + l4 * 4 + r;
                float val = acc[mb][nb][r] + bv;
                if (mode == 0) val *= SCLQ;  // fold softmax scale+log2e into Q
                if (mode == 3) {
                    ((float*)Cout)[(size_t)m * 512 + n] = val;
                } else {
                    int b = m >> 11, tok = m & 2047;
                    int h = n >> 6, d = n & 63;
                    short* o = (short*)Cout;
                    if (mode == 2)
                        o[((size_t)(b * 8 + h) * 64 + d) * 2048 + tok] = (short)f2bf(val);
                    else
                        o[((size_t)(b * 8 + h) * 2048 + tok) * 64 + d] = (short)f2bf(val);
                }
            }
        }
    }
}

// ---------------- masked flash attention (KV-split x4, bh->XCD pinning) ----------------
// 1-D grid of 2048; xcd = lid&7 pins bh = xcd*4 + ((lid>>3)>>6) so each XCD serves
// exactly 4 (b,h) and that bh's K/V (512 KB) stays L2-resident across its 64 q-blocks.
// Block owns 32 q-rows; wave w handles kv-tiles [w*8, w*8+8). Swapped QK^T
// (S^T: col=l15=q, row=l4*4+r=k); mask applied as MFMA C-init (0/-1e30);
// Q pre-scaled so logits are log2-domain. Partials combined via LDS in TWO
// qs-halves reusing the P-buffer region -> LDS high-water 17.2 KB (5-6 blocks/CU).
__global__ __launch_bounds__(256, 3) void attn_kernel(
    const short* __restrict__ Q, const short* __restrict__ K,
    const short* __restrict__ VT, const unsigned long long* __restrict__ mp,
    short* __restrict__ AO)
{
    // LDS map, phase 1 (loop):    [0,16384) per-wave P buffers (wid*4096)
    //          phase 2 (combine): [0,16640) Of partials f32 (one qs-half, 260 B/row)
    //                             [16640,17152) (m,l) float2 per (wave, q)
    __shared__ char lds[17152];
    const int lane = threadIdx.x & 63;
    const int wid = threadIdx.x >> 6;
    const int l15 = lane & 15, l4 = lane >> 4;
    // bh->XCD locality decode (bijective over 2048 blocks)
    const int lid = blockIdx.x;
    const int xcd = lid & 7, j = lid >> 3;
    const int bhi = (xcd << 2) | (j >> 6);
    const int b = bhi >> 3, h = bhi & 7;
    const int q0 = (j & 63) * 32;
    const size_t bh = (size_t)b * 8 + h;
    const short* Qp = Q + (bh * 2048 + q0) * 64;
    const short* Kp = K + (bh * 2048 + (size_t)wid * 512) * 64;  // wave's kv quarter
    const short* Vp = VT + bh * 64 * 2048;
    const int ktb = wid * 8;
    char* Pw = lds + wid * 4096;
    const int sw = (l15 & 7) << 4;  // per-row XOR swizzle (G4)

    // Q fragments (persistent): aq[qs][ds] = Q[q0+qs*16+l15][ds*32 + l4*8 + j]
    bf16x8 aq[2][2];
#pragma unroll
    for (int qs = 0; qs < 2; ++qs)
#pragma unroll
        for (int ds = 0; ds < 2; ++ds)
            aq[qs][ds] = *(const bf16x8*)(Qp + (qs * 16 + l15) * 64 + ds * 32 + l4 * 8);

    const f32x4 zero = {0.f, 0.f, 0.f, 0.f};
    f32x4 o[2][4];
    float mrun[2] = {-1e30f, -1e30f}, lrun[2] = {0.f, 0.f};
#pragma unroll
    for (int qs = 0; qs < 2; ++qs)
#pragma unroll
        for (int dt = 0; dt < 4; ++dt) o[qs][dt] = zero;

    const unsigned long long* mr0 = mp + ((size_t)b * 2048 + q0 + l15) * 32 + ktb;
    const unsigned long long* mr1 = mr0 + 16 * 32;

    // single-buffered K/V frags; prefetch issued after last consumer (WAR, in-order)
    bf16x8 kf[4][2], vf[4][2];
#pragma unroll
    for (int kb = 0; kb < 4; ++kb)
#pragma unroll
        for (int ds = 0; ds < 2; ++ds)
            kf[kb][ds] = *(const bf16x8*)(Kp + (kb * 16 + l15) * 64 + ds * 32 + l4 * 8);
#pragma unroll
    for (int dt = 0; dt < 4; ++dt)
#pragma unroll
        for (int ks = 0; ks < 2; ++ks)
            vf[dt][ks] = *(const bf16x8*)(Vp + (size_t)(dt * 16 + l15) * 2048 +
                                          ktb * 64 + ks * 32 + l4 * 8);
    unsigned long long mwq0 = mr0[0], mwq1 = mr1[0];
    unsigned long long mwn0 = 0, mwn1 = 0;

// QK^T with mask as C-init: sv[kb] = K*Q + (bit ? 0 : -1e30)
#define QKT_BLOCK(QS, MWQ)                                                        \
    {                                                                             \
        unsigned long long ms_ = (MWQ) >> (l4 * 4);                               \
        unsigned w0_ = (unsigned)ms_, w1_ = (unsigned)(ms_ >> 32);                \
        _Pragma("unroll") for (int kb = 0; kb < 4; ++kb) {                        \
            unsigned ws_ = (kb & 2) ? w1_ : w0_;                                  \
            f32x4 ini;                                                            \
            _Pragma("unroll") for (int r = 0; r < 4; ++r)                         \
                ini[r] = (ws_ & (1u << (((kb & 1) << 4) + r))) ? 0.f : -1e30f;    \
            sv[kb] = mfma16(kf[kb][1], aq[QS][1],                                 \
                            mfma16(kf[kb][0], aq[QS][0], ini));                   \
        }                                                                         \
    }

// tree max -> 2 shfl -> defer-max rescale -> exp2 -> pack -> swizzled P write
#define SM_BLOCK(QS)                                                              \
    {                                                                             \
        float pk0 = fmaxf(fmaxf(sv[0][0], sv[0][1]), fmaxf(sv[0][2], sv[0][3]));  \
        float pk1 = fmaxf(fmaxf(sv[1][0], sv[1][1]), fmaxf(sv[1][2], sv[1][3]));  \
        float pk2 = fmaxf(fmaxf(sv[2][0], sv[2][1]), fmaxf(sv[2][2], sv[2][3]));  \
        float pk3 = fmaxf(fmaxf(sv[3][0], sv[3][1]), fmaxf(sv[3][2], sv[3][3]));  \
        float pm = fmaxf(fmaxf(pk0, pk1), fmaxf(pk2, pk3));                       \
        pm = fmaxf(pm, __shfl_xor(pm, 16, 64));                                   \
        pm = fmaxf(pm, __shfl_xor(pm, 32, 64));                                   \
        if (__any(pm > mrun[QS] + 8.f)) {                                         \
            float mnew = fmaxf(mrun[QS], pm);                                     \
            float al = exp2f(mrun[QS] - mnew);                                    \
            mrun[QS] = mnew; lrun[QS] *= al;                                      \
            _Pragma("unroll") for (int r = 0; r < 4; ++r) {                       \
                float aR = __shfl(al, l4 * 4 + r, 64);                            \
                _Pragma("unroll") for (int dt = 0; dt < 4; ++dt)                  \
                    o[QS][dt][r] *= aR;                                           \
            }                                                                     \
        }                                                                         \
        float sk0, sk1, sk2, sk3;                                                 \
        _Pragma("unroll") for (int kb = 0; kb < 4; ++kb) {                        \
            float e0 = exp2f(sv[kb][0] - mrun[QS]);                               \
            float e1 = exp2f(sv[kb][1] - mrun[QS]);                               \
            float e2 = exp2f(sv[kb][2] - mrun[QS]);                               \
            float e3 = exp2f(sv[kb][3] - mrun[QS]);                               \
            float sk_ = (e0 + e1) + (e2 + e3);                                    \
            if (kb == 0) sk0 = sk_; else if (kb == 1) sk1 = sk_;                  \
            else if (kb == 2) sk2 = sk_; else sk3 = sk_;                          \
            unsigned u0, u1;                                                      \
            asm("v_cvt_pk_bf16_f32 %0, %1, %2" : "=v"(u0) : "v"(e0), "v"(e1));    \
            asm("v_cvt_pk_bf16_f32 %0, %1, %2" : "=v"(u1) : "v"(e2), "v"(e3));    \
            uint2 wv; wv.x = u0; wv.y = u1;                                       \
            *(uint2*)(Pw + (QS) * 2048 + l15 * 128 + ((kb * 32 + l4 * 8) ^ sw)) = wv; \
        }                                                                         \
        float ls = (sk0 + sk1) + (sk2 + sk3);                                     \
        ls += __shfl_xor(ls, 16, 64);                                             \
        ls += __shfl_xor(ls, 32, 64);                                             \
        lrun[QS] += ls;                                                           \
    }

#pragma unroll
    for (int lt = 0; lt < 8; ++lt) {
        f32x4 sv[4];
        QKT_BLOCK(0, mwq0)
        SM_BLOCK(0)
        QKT_BLOCK(1, mwq1)
        if (lt < 7) {  // K+mask prefetch for lt+1 (kf fully consumed above)
#pragma unroll
            for (int kb = 0; kb < 4; ++kb)
#pragma unroll
                for (int ds = 0; ds < 2; ++ds)
                    kf[kb][ds] = *(const bf16x8*)(Kp + ((lt + 1) * 64 + kb * 16 + l15) * 64 +
                                                  ds * 32 + l4 * 8);
            mwn0 = mr0[lt + 1]; mwn1 = mr1[lt + 1];
        }
        SM_BLOCK(1)
        asm volatile("s_waitcnt lgkmcnt(0)" ::: "memory");  // P writes visible to own wave
        // PV: A = P[q=l15][k contiguous], B = vf (col=l15=d)
#pragma unroll
        for (int qs = 0; qs < 2; ++qs)
#pragma unroll
            for (int ks = 0; ks < 2; ++ks) {
                bf16x8 ap = *(const bf16x8*)(Pw + qs * 2048 + l15 * 128 +
                                             ((ks * 64 + l4 * 16) ^ sw));
#pragma unroll
                for (int dt = 0; dt < 4; ++dt)
                    o[qs][dt] = mfma16(ap, vf[dt][ks], o[qs][dt]);
            }
        if (lt < 7) {  // V prefetch for lt+1 (vf fully consumed by PV above)
#pragma unroll
            for (int dt = 0; dt < 4; ++dt)
#pragma unroll
                for (int ks = 0; ks < 2; ++ks)
                    vf[dt][ks] = *(const bf16x8*)(Vp + (size_t)(dt * 16 + l15) * 2048 +
                                                  (ktb + lt + 1) * 64 + ks * 32 + l4 * 8);
            mwq0 = mwn0; mwq1 = mwn1;
        }
    }
#undef QKT_BLOCK
#undef SM_BLOCK

    // ---- combine the 4 kv-quarter partials through LDS, one qs-half at a time ----
    // Per half: wave writes its 16q x 64d f32 partial (stride 260 B) + (m,l);
    // then 256 threads reduce 4 partials -> bf16 AO. LDS high-water 17152 B.
#pragma unroll
    for (int qs = 0; qs < 2; ++qs) {
        __syncthreads();  // previous phase's LDS reads complete
#pragma unroll
        for (int dt = 0; dt < 4; ++dt)
#pragma unroll
            for (int r = 0; r < 4; ++r)
                *(float*)(lds + wid * 4160 + (l4 * 4 + r) * 260 + (dt * 16 + l15) * 4)
                    = o[qs][dt][r];
        if (l4 == 0) {
            float2 v; v.x = mrun[qs]; v.y = lrun[qs];
            *(float2*)(lds + 16640 + (wid * 16 + l15) * 8) = v;
        }
        __syncthreads();
        {
            int q = threadIdx.x >> 4;          // 0..15 within this qs-half
            int d0 = (threadIdx.x & 15) * 4;   // 0..60
            float mW[4], lW[4];
#pragma unroll
            for (int w = 0; w < 4; ++w) {
                float2 v = *(const float2*)(lds + 16640 + (w * 16 + q) * 8);
                mW[w] = v.x; lW[w] = v.y;
            }
            float m = fmaxf(fmaxf(mW[0], mW[1]), fmaxf(mW[2], mW[3]));
            float wg[4]; float lsum = 0.f;
#pragma unroll
            for (int w = 0; w < 4; ++w) { wg[w] = exp2f(mW[w] - m); lsum += lW[w] * wg[w]; }
            float inv = 1.0f / lsum;
            float a0 = 0.f, a1 = 0.f, a2 = 0.f, a3 = 0.f;
#pragma unroll
            for (int w = 0; w < 4; ++w) {
                const float* p = (const float*)(lds + w * 4160 + q * 260 + d0 * 4);
                a0 += wg[w] * p[0]; a1 += wg[w] * p[1];
                a2 += wg[w] * p[2]; a3 += wg[w] * p[3];
            }
            short4 ov;
            ov.x = (short)f2bf(a0 * inv); ov.y = (short)f2bf(a1 * inv);
            ov.z = (short)f2bf(a2 * inv); ov.w = (short)f2bf(a3 * inv);
            *(short4*)(AO + ((size_t)b * 2048 + q0 + qs * 16 + q) * 512 + h * 64 + d0) = ov;
        }
    }
}

// ---------------- launcher ----------------
extern "C" void kernel_launch(void* const* d_in, const int* in_sizes, int n_in,
                              void* d_out, int out_size, void* d_ws, size_t ws_size,
                              hipStream_t stream) {
    const float* q  = (const float*)d_in[0];
    const float* k  = (const float*)d_in[1];
    const float* v  = (const float*)d_in[2];
    const int*   gm = (const int*)d_in[3];
    const float* Wq = (const float*)d_in[4];  const float* bq = (const float*)d_in[5];
    const float* Wk = (const float*)d_in[6];  const float* bk = (const float*)d_in[7];
    const float* Wv = (const float*)d_in[8];  const float* bv = (const float*)d_in[9];
    const float* Wo = (const float*)d_in[10]; const float* bo = (const float*)d_in[11];

    char* ws = (char*)d_ws;
    short* Xq  = (short*)(ws + 0);
    short* Xk  = (short*)(ws + 8388608);
    short* Xv  = (short*)(ws + 16777216);
    short* WqT = (short*)(ws + 25165824);
    short* WkT = (short*)(ws + 25690112);
    short* WvT = (short*)(ws + 26214400);
    short* WoT = (short*)(ws + 26738688);
    short* Qw  = (short*)(ws + 27262976);    // [b,h,tok,d] (pre-scaled)
    short* Kw  = (short*)(ws + 35651584);    // [b,h,tok,d]
    short* VTw = (short*)(ws + 44040192);    // [b,h,d,tok]
    short* AO  = (short*)(ws + 52428800);    // attn out [b,tok,h*64+d]
    unsigned long long* MP = (unsigned long long*)(ws + 60817408);

    cvt_x_kernel<<<dim3(4096, 3), 256, 0, stream>>>(q, k, v, Xq, Xk, Xv);
    cvt_wt_kernel<<<dim3(128, 4), 256, 0, stream>>>(Wq, Wk, Wv, Wo, WqT, WkT, WvT, WoT);
    pack_mask_kernel<<<dim3(2048), 256, 0, stream>>>(gm, MP);

    gemm_kernel<<<dim3(4, 64), 256, 0, stream>>>(Xq, WqT, bq, Qw, 0);
    gemm_kernel<<<dim3(4, 64), 256, 0, stream>>>(Xk, WkT, bk, Kw, 1);
    gemm_kernel<<<dim3(4, 64), 256, 0, stream>>>(Xv, WvT, bv, VTw, 2);

    attn_kernel<<<dim3(2048), 256, 0, stream>>>(Qw, Kw, VTw, MP, AO);

    gemm_kernel<<<dim3(4, 64), 256, 0, stream>>>(AO, WoT, bo, (void*)d_out, 3);
}

// Round 7
// 173.651 us; speedup vs baseline: 2.0943x; 1.4036x over previous
//
#include <hip/hip_runtime.h>
#include <stdint.h>

// E=512, H=8, D=64, B=4, Nq=Nk=2048
// bf16 MFMA pipeline: cvt -> QKV proj GEMM (z-batched, Q pre-scaled) -> flash attn
// (8-wave block, LDS K/V dbuf, swapped QK^T 16x16, in-register softmax AND P,
//  mask as MFMA C-init, XCD pinning) -> out proj GEMM

typedef __attribute__((ext_vector_type(8))) short bf16x8;  // 8 bf16 in 4 VGPRs
typedef __attribute__((ext_vector_type(4))) float f32x4;

#define SCLQ 0.18033688011112042f  // 0.125 * log2(e): logits emerge in log2 domain

static __device__ __forceinline__ unsigned short f2bf(float f) {
    union { float f; unsigned u; } x; x.f = f;
    unsigned r = x.u + 0x7fffu + ((x.u >> 16) & 1u);  // RTN-even
    return (unsigned short)(r >> 16);
}

static __device__ __forceinline__ f32x4 mfma16(bf16x8 a, bf16x8 b, f32x4 c) {
    return __builtin_amdgcn_mfma_f32_16x16x32_bf16(a, b, c, 0, 0, 0);
}

#define GLOAD_LDS16(g, l)                                                            \
    __builtin_amdgcn_global_load_lds((const __attribute__((address_space(1))) void*)(g), \
                                     (__attribute__((address_space(3))) void*)(l), 16, 0, 0)

// ---------------- conversion kernels ----------------

__global__ __launch_bounds__(256) void cvt_x_kernel(
    const float* __restrict__ xq, const float* __restrict__ xk, const float* __restrict__ xv,
    short* __restrict__ oq, short* __restrict__ ok, short* __restrict__ ov)
{
    const float* src = (blockIdx.y == 0) ? xq : (blockIdx.y == 1) ? xk : xv;
    short* dst = (blockIdx.y == 0) ? oq : (blockIdx.y == 1) ? ok : ov;
    size_t i = (size_t)blockIdx.x * 256 + threadIdx.x;
    float4 v = ((const float4*)src)[i];
    short4 o;
    o.x = (short)f2bf(v.x); o.y = (short)f2bf(v.y);
    o.z = (short)f2bf(v.z); o.w = (short)f2bf(v.w);
    ((short4*)dst)[i] = o;
}

__global__ __launch_bounds__(256) void cvt_wt_kernel(
    const float* __restrict__ Wq, const float* __restrict__ Wk,
    const float* __restrict__ Wv, const float* __restrict__ Wo,
    short* __restrict__ WqT, short* __restrict__ WkT,
    short* __restrict__ WvT, short* __restrict__ WoT)
{
    int z = blockIdx.y;
    const float* W = (z == 0) ? Wq : (z == 1) ? Wk : (z == 2) ? Wv : Wo;
    short* WT = (z == 0) ? WqT : (z == 1) ? WkT : (z == 2) ? WvT : WoT;
    int t = blockIdx.x * 256 + threadIdx.x;
    int n = t & 511;
    int k0 = (t >> 9) * 8;
    union { short s[8]; int4 v; } u;
#pragma unroll
    for (int j = 0; j < 8; ++j) u.s[j] = (short)f2bf(W[(size_t)(k0 + j) * 512 + n]);
    *(int4*)(WT + (size_t)n * 512 + k0) = u.v;
}

// mask (4-byte elems, nonzero = keep) -> packed bits; word w covers k=[w*64,w*64+64)
__global__ __launch_bounds__(256) void pack_mask_kernel(
    const int* __restrict__ mask, unsigned long long* __restrict__ mp)
{
    int lane = threadIdx.x & 63;
    int row = blockIdx.x * 4 + (threadIdx.x >> 6);  // b*2048+q
    const int* mrow = mask + (size_t)row * 2048;
#pragma unroll 4
    for (int w = 0; w < 32; ++w) {
        unsigned long long bits = __ballot(mrow[w * 64 + lane] != 0);
        if (lane == 0) mp[(size_t)row * 32 + w] = bits;
    }
}

// ---------------- GEMM body: C[8192x512] = A[8192x512] @ W (+bias) ----------------
// mode 0: Q -> [b,h,tok,d] bf16, pre-scaled ; 1: K -> [b,h,tok,d] ; 2: V -> [b,h,d,tok]
// mode 3: fp32 row-major out
static __device__ __forceinline__ void gemm_body(
    const short* __restrict__ A, const short* __restrict__ BT,
    const float* __restrict__ bias, void* __restrict__ Cout, int mode,
    char* lds, int bx, int by)
{
    const int tid = threadIdx.x;
    const int lane = tid & 63;
    const int wid = tid >> 6;
    const int l15 = lane & 15, l4 = lane >> 4;
    const int m0 = by * 128;
    const int n0 = bx * 128;
    const int wr = wid >> 1, wc = wid & 1;

    f32x4 zero = {0.f, 0.f, 0.f, 0.f};
    f32x4 acc[4][4];
#pragma unroll
    for (int i = 0; i < 4; ++i)
#pragma unroll
        for (int j = 0; j < 4; ++j) acc[i][j] = zero;

    char* Alds = lds;
    char* Blds = lds + 16384;

    for (int t = 0; t < 8; ++t) {
        const int k0 = t * 64;
#pragma unroll
        for (int s = 0; s < 4; ++s) {
            int p = s * 256 + tid;
            int r = p >> 3, c = p & 7;
            GLOAD_LDS16(A + (size_t)(m0 + r) * 512 + k0 + 8 * (c ^ (r & 7)),
                        Alds + s * 4096 + wid * 1024);
            GLOAD_LDS16(BT + (size_t)(n0 + r) * 512 + k0 + 8 * (c ^ (r & 7)),
                        Blds + s * 4096 + wid * 1024);
        }
        __syncthreads();
#pragma unroll
        for (int ks = 0; ks < 2; ++ks) {
            bf16x8 af[4], bfr[4];
#pragma unroll
            for (int mb = 0; mb < 4; ++mb) {
                int row = wr * 64 + mb * 16 + l15;
                af[mb] = *(const bf16x8*)(Alds + row * 128 +
                                          ((ks * 64 + l4 * 16) ^ ((row & 7) << 4)));
            }
#pragma unroll
            for (int nb = 0; nb < 4; ++nb) {
                int row = wc * 64 + nb * 16 + l15;
                bfr[nb] = *(const bf16x8*)(Blds + row * 128 +
                                           ((ks * 64 + l4 * 16) ^ ((row & 7) << 4)));
            }
#pragma unroll
            for (int mb = 0; mb < 4; ++mb)
#pragma unroll
                for (int nb = 0; nb < 4; ++nb)
                    acc[mb][nb] = mfma16(af[mb], bfr[nb], acc[mb][nb]);
        }
        __syncthreads();
    }

#pragma unroll
    for (int nb = 0; nb < 4; ++nb) {
        int n = n0 + wc * 64 + nb * 16 + l15;
        float bv = bias[n];
#pragma unroll
        for (int mb = 0; mb < 4; ++mb) {
#pragma unroll
            for (int r = 0; r < 4; ++r) {
                int m = m0 + wr * 64 + mb * 16 + l4 * 4 + r;
                float val = acc[mb][nb][r] + bv;
                if (mode == 0) val *= SCLQ;  // fold softmax scale+log2e into Q
                if (mode == 3) {
                    ((float*)Cout)[(size_t)m * 512 + n] = val;
                } else {
                    int b = m >> 11, tok = m & 2047;
                    int h = n >> 6, d = n & 63;
                    short* o = (short*)Cout;
                    if (mode == 2)
                        o[((size_t)(b * 8 + h) * 64 + d) * 2048 + tok] = (short)f2bf(val);
                    else
                        o[((size_t)(b * 8 + h) * 2048 + tok) * 64 + d] = (short)f2bf(val);
                }
            }
        }
    }
}

// z-batched QKV projection: blockIdx.z selects {Q,K,V}
__global__ __launch_bounds__(256) void gemm_qkv_kernel(
    const short* __restrict__ Xq, const short* __restrict__ Xk, const short* __restrict__ Xv,
    const short* __restrict__ WqT, const short* __restrict__ WkT, const short* __restrict__ WvT,
    const float* __restrict__ bq, const float* __restrict__ bk, const float* __restrict__ bv,
    short* __restrict__ Qw, short* __restrict__ Kw, short* __restrict__ VTw)
{
    __shared__ char lds[32768];
    int z = blockIdx.z;
    const short* A = (z == 0) ? Xq : (z == 1) ? Xk : Xv;
    const short* BT = (z == 0) ? WqT : (z == 1) ? WkT : WvT;
    const float* bias = (z == 0) ? bq : (z == 1) ? bk : bv;
    void* Cout = (z == 0) ? (void*)Qw : (z == 1) ? (void*)Kw : (void*)VTw;
    gemm_body(A, BT, bias, Cout, z, lds, blockIdx.x, blockIdx.y);
}

__global__ __launch_bounds__(256) void gemm_kernel(
    const short* __restrict__ A, const short* __restrict__ BT,
    const float* __restrict__ bias, void* __restrict__ Cout, int mode)
{
    __shared__ char lds[32768];
    gemm_body(A, BT, bias, Cout, mode, lds, blockIdx.x, blockIdx.y);
}

// ---------------- masked flash attention: 8-wave, 16x16 MFMA, in-register P ----------------
// grid 256 = 8 XCD x 4 bh x 8 q-chunks (xcd = lid&7 pins bh to one XCD's L2).
// Block: 512 thr = 8 waves; wave owns 32 q (2 col-blocks of 16); KVBLK=64 shared in LDS
// (global_load_lds w=16, dbuf, XOR-swizzled via pre-swizzled global source — the exact
//  staging pattern validated by the passing GEMM).
// Swapped QK^T (verified 16x16 layouts): S^T col=l15=q, row=l4*4+r=k (per 16-token block).
// Lane holds 16 S-values per q-block -> in-lane tree max + 2 shfl_xor merges.
// In-register P via sigma16(l4,j)=l4*4+(j&3)+16*(j>>2): A-frags = in-order cvt_pk packs of
// own regs; V B-frags = two ds_read_b64 at matching sigma16 offsets. Mask as MFMA C-init.
__global__ __launch_bounds__(512) void attn_kernel(
    const short* __restrict__ Q, const short* __restrict__ K,
    const short* __restrict__ VT, const unsigned long long* __restrict__ mp,
    short* __restrict__ AO)
{
    __shared__ char lds[32768];  // K dbuf 2x8KB @0; V dbuf 2x8KB @16384
    const int tid = threadIdx.x;
    const int lane = tid & 63;
    const int wid = tid >> 6;
    const int l15 = lane & 15, l4 = lane >> 4;
    const int lid = blockIdx.x;
    const int xcd = lid & 7, jj = lid >> 3;
    const int bhi = (xcd << 2) | (jj >> 3);
    const int b = bhi >> 3, h = bhi & 7;
    const int q0 = (jj & 7) * 256 + wid * 32;
    const short* Qp = Q + ((size_t)bhi * 2048 + q0) * 64;
    const short* Kp = K + (size_t)bhi * 2048 * 64;
    const short* Vp = VT + (size_t)bhi * 64 * 2048;

    // staging map: thread t -> row t>>3 (64 rows), 16B chunk t&7, pre-swizzled source
    const int srow = tid >> 3;
    const int sgo = 8 * ((tid & 7) ^ (srow & 7));
    const int swl = l15 & 7;  // read-side swizzle key (row & 7)

    // Q B-frags (verified 16x16 pattern): qb[qcb][dc] = Q[q0+qcb*16+l15][dc*32+l4*8+j]
    bf16x8 qb[2][2];
#pragma unroll
    for (int qcb = 0; qcb < 2; ++qcb)
#pragma unroll
        for (int dc = 0; dc < 2; ++dc)
            qb[qcb][dc] = *(const bf16x8*)(Qp + (qcb * 16 + l15) * 64 + dc * 32 + l4 * 8);

    const f32x4 zero = {0.f, 0.f, 0.f, 0.f};
    f32x4 o[2][4];  // o[qcb][dt]: q = qcb*16 + l4*4 + r, d = dt*16 + l15
#pragma unroll
    for (int qcb = 0; qcb < 2; ++qcb)
#pragma unroll
        for (int dt = 0; dt < 4; ++dt) o[qcb][dt] = zero;
    float mrun[2] = {-1e30f, -1e30f}, lrun[2] = {0.f, 0.f};

    const unsigned long long* mr0 = mp + ((size_t)b * 2048 + q0 + l15) * 32;
    const unsigned long long* mr1 = mr0 + 16 * 32;

    // prologue: stage tile 0 into buf 0
    GLOAD_LDS16(Kp + (size_t)srow * 64 + sgo, lds + wid * 1024);
    GLOAD_LDS16(Vp + (size_t)srow * 2048 + sgo, lds + 16384 + wid * 1024);
    unsigned long long mw0 = mr0[0], mw1 = mr1[0];
    __syncthreads();

    for (int kt = 0; kt < 32; ++kt) {
        const int cur = kt & 1;
        char* Kc = lds + cur * 8192;
        char* Vc = lds + 16384 + cur * 8192;
        if (kt < 31) {  // stage next tile into other buffer
            GLOAD_LDS16(Kp + ((size_t)(kt + 1) * 64 + srow) * 64 + sgo,
                        lds + (cur ^ 1) * 8192 + wid * 1024);
            GLOAD_LDS16(Vp + (size_t)srow * 2048 + (kt + 1) * 64 + sgo,
                        lds + 16384 + (cur ^ 1) * 8192 + wid * 1024);
        }
        unsigned long long mn0 = 0, mn1 = 0;
        if (kt < 31) { mn0 = mr0[kt + 1]; mn1 = mr1[kt + 1]; }

        // K A-frags (shared by both q-blocks): row = tb*16+l15 (token), d = dc*32+l4*8+j
        bf16x8 ka[4][2];
#pragma unroll
        for (int tb = 0; tb < 4; ++tb)
#pragma unroll
            for (int dc = 0; dc < 2; ++dc)
                ka[tb][dc] = *(const bf16x8*)(Kc + (tb * 16 + l15) * 128 +
                                              16 * ((dc * 4 + l4) ^ swl));

        // QK^T with mask C-init: sv[tb][r] = S^T[token tb*16+l4*4+r][q] + (bit?0:-1e30)
        f32x4 sv0[4], sv1[4];
#pragma unroll
        for (int tb = 0; tb < 4; ++tb) {
            unsigned u0 = (unsigned)(mw0 >> (tb * 16 + l4 * 4));
            unsigned u1 = (unsigned)(mw1 >> (tb * 16 + l4 * 4));
            f32x4 i0, i1;
#pragma unroll
            for (int r = 0; r < 4; ++r) {
                i0[r] = (u0 & (1u << r)) ? 0.f : -1e30f;
                i1[r] = (u1 & (1u << r)) ? 0.f : -1e30f;
            }
            sv0[tb] = mfma16(ka[tb][1], qb[0][1], mfma16(ka[tb][0], qb[0][0], i0));
            sv1[tb] = mfma16(ka[tb][1], qb[1][1], mfma16(ka[tb][0], qb[1][0], i1));
        }

        // V B-frags at sigma16 offsets: element j <-> token kb*32 + l4*4 + (j&3) + 16*(j>>2)
        bf16x8 vb[4][2];
#pragma unroll
        for (int dt = 0; dt < 4; ++dt)
#pragma unroll
            for (int kb = 0; kb < 2; ++kb) {
                const char* vr = Vc + (dt * 16 + l15) * 128;
                uint2 x = *(const uint2*)(vr + 16 * ((kb * 4 + (l4 >> 1)) ^ swl) +
                                          (l4 & 1) * 8);
                uint2 y = *(const uint2*)(vr + 16 * ((kb * 4 + 2 + (l4 >> 1)) ^ swl) +
                                          (l4 & 1) * 8);
                uint4 t; t.x = x.x; t.y = x.y; t.z = y.x; t.w = y.y;
                vb[dt][kb] = *(bf16x8*)&t;
            }

        // in-lane tree max (depth 4) + 2 shfl_xor merges per q-block
        f32x4 m0v, m1v;
#pragma unroll
        for (int r = 0; r < 4; ++r) {
            m0v[r] = fmaxf(fmaxf(sv0[0][r], sv0[1][r]), fmaxf(sv0[2][r], sv0[3][r]));
            m1v[r] = fmaxf(fmaxf(sv1[0][r], sv1[1][r]), fmaxf(sv1[2][r], sv1[3][r]));
        }
        float pm0 = fmaxf(fmaxf(m0v[0], m0v[1]), fmaxf(m0v[2], m0v[3]));
        float pm1 = fmaxf(fmaxf(m1v[0], m1v[1]), fmaxf(m1v[2], m1v[3]));
        pm0 = fmaxf(pm0, __shfl_xor(pm0, 16, 64));
        pm0 = fmaxf(pm0, __shfl_xor(pm0, 32, 64));
        pm1 = fmaxf(pm1, __shfl_xor(pm1, 16, 64));
        pm1 = fmaxf(pm1, __shfl_xor(pm1, 32, 64));

        // defer-max (T13): rescale only when a row max grew past THR=8 (log2 units)
        int need = (pm0 > mrun[0] + 8.f) | (pm1 > mrun[1] + 8.f);
        if (__any(need)) {
#pragma unroll
            for (int qcb = 0; qcb < 2; ++qcb) {
                float pmq = qcb ? pm1 : pm0;
                float mnew = fmaxf(mrun[qcb], pmq);
                float al = exp2f(mrun[qcb] - mnew);
                mrun[qcb] = mnew; lrun[qcb] *= al;
#pragma unroll
                for (int r = 0; r < 4; ++r) {
                    float alr = __shfl(al, l4 * 4 + r, 64);
#pragma unroll
                    for (int dt = 0; dt < 4; ++dt) o[qcb][dt][r] *= alr;
                }
            }
        }

        // exp2 in place + per-lane partial sums (lane's 16 tokens; merged at epilogue)
#pragma unroll
        for (int tb = 0; tb < 4; ++tb)
#pragma unroll
            for (int r = 0; r < 4; ++r) {
                sv0[tb][r] = exp2f(sv0[tb][r] - mrun[0]);
                sv1[tb][r] = exp2f(sv1[tb][r] - mrun[1]);
            }
        {
            f32x4 t0 = (sv0[0] + sv0[1]) + (sv0[2] + sv0[3]);
            f32x4 t1 = (sv1[0] + sv1[1]) + (sv1[2] + sv1[3]);
            lrun[0] += (t0[0] + t0[1]) + (t0[2] + t0[3]);
            lrun[1] += (t1[0] + t1[1]) + (t1[2] + t1[3]);
        }

        // pack P A-frags: pa[qcb][kb] = in-order cvt_pk of own regs (sigma16-matched)
        bf16x8 pa[2][2];
#define PACK8(DST, SA, SB)                                                              \
        { uint4 t_;                                                                     \
          asm("v_cvt_pk_bf16_f32 %0, %1, %2" : "=v"(t_.x) : "v"(SA[0]), "v"(SA[1]));    \
          asm("v_cvt_pk_bf16_f32 %0, %1, %2" : "=v"(t_.y) : "v"(SA[2]), "v"(SA[3]));    \
          asm("v_cvt_pk_bf16_f32 %0, %1, %2" : "=v"(t_.z) : "v"(SB[0]), "v"(SB[1]));    \
          asm("v_cvt_pk_bf16_f32 %0, %1, %2" : "=v"(t_.w) : "v"(SB[2]), "v"(SB[3]));    \
          DST = *(bf16x8*)&t_; }
        PACK8(pa[0][0], sv0[0], sv0[1])
        PACK8(pa[0][1], sv0[2], sv0[3])
        PACK8(pa[1][0], sv1[0], sv1[1])
        PACK8(pa[1][1], sv1[2], sv1[3])
#undef PACK8

        // PV: o[qcb][dt] += P(kb) x V(kb), contraction over 2 x 32 tokens
#pragma unroll
        for (int dt = 0; dt < 4; ++dt) {
            o[0][dt] = mfma16(pa[0][1], vb[dt][1], mfma16(pa[0][0], vb[dt][0], o[0][dt]));
            o[1][dt] = mfma16(pa[1][1], vb[dt][1], mfma16(pa[1][0], vb[dt][0], o[1][dt]));
        }

        mw0 = mn0; mw1 = mn1;
        __syncthreads();  // drains stage loads + LDS reads; swap buffers
    }

    // epilogue: merge l4-group partial sums, normalize, store
#pragma unroll
    for (int qcb = 0; qcb < 2; ++qcb) {
        float lt = lrun[qcb];
        lt += __shfl_xor(lt, 16, 64);
        lt += __shfl_xor(lt, 32, 64);
        float inv = 1.0f / lt;  // for q = q0 + qcb*16 + l15
#pragma unroll
        for (int r = 0; r < 4; ++r) {
            float invr = __shfl(inv, l4 * 4 + r, 64);
            size_t base = ((size_t)b * 2048 + q0 + qcb * 16 + l4 * 4 + r) * 512 + h * 64;
#pragma unroll
            for (int dt = 0; dt < 4; ++dt)
                AO[base + dt * 16 + l15] = (short)f2bf(o[qcb][dt][r] * invr);
        }
    }
}

// ---------------- launcher ----------------
extern "C" void kernel_launch(void* const* d_in, const int* in_sizes, int n_in,
                              void* d_out, int out_size, void* d_ws, size_t ws_size,
                              hipStream_t stream) {
    const float* q  = (const float*)d_in[0];
    const float* k  = (const float*)d_in[1];
    const float* v  = (const float*)d_in[2];
    const int*   gm = (const int*)d_in[3];
    const float* Wq = (const float*)d_in[4];  const float* bq = (const float*)d_in[5];
    const float* Wk = (const float*)d_in[6];  const float* bk = (const float*)d_in[7];
    const float* Wv = (const float*)d_in[8];  const float* bv = (const float*)d_in[9];
    const float* Wo = (const float*)d_in[10]; const float* bo = (const float*)d_in[11];

    char* ws = (char*)d_ws;
    short* Xq  = (short*)(ws + 0);
    short* Xk  = (short*)(ws + 8388608);
    short* Xv  = (short*)(ws + 16777216);
    short* WqT = (short*)(ws + 25165824);
    short* WkT = (short*)(ws + 25690112);
    short* WvT = (short*)(ws + 26214400);
    short* WoT = (short*)(ws + 26738688);
    short* Qw  = (short*)(ws + 27262976);    // [b,h,tok,d] (pre-scaled)
    short* Kw  = (short*)(ws + 35651584);    // [b,h,tok,d]
    short* VTw = (short*)(ws + 44040192);    // [b,h,d,tok]
    short* AO  = (short*)(ws + 52428800);    // attn out [b,tok,h*64+d]
    unsigned long long* MP = (unsigned long long*)(ws + 60817408);

    cvt_x_kernel<<<dim3(4096, 3), 256, 0, stream>>>(q, k, v, Xq, Xk, Xv);
    cvt_wt_kernel<<<dim3(128, 4), 256, 0, stream>>>(Wq, Wk, Wv, Wo, WqT, WkT, WvT, WoT);
    pack_mask_kernel<<<dim3(2048), 256, 0, stream>>>(gm, MP);

    gemm_qkv_kernel<<<dim3(4, 64, 3), 256, 0, stream>>>(Xq, Xk, Xv, WqT, WkT, WvT,
                                                        bq, bk, bv, Qw, Kw, VTw);

    attn_kernel<<<dim3(256), 512, 0, stream>>>(Qw, Kw, VTw, MP, AO);

    gemm_kernel<<<dim3(4, 64), 256, 0, stream>>>(AO, WoT, bo, (void*)d_out, 3);
}

// Round 9
// 168.317 us; speedup vs baseline: 2.1607x; 1.0317x over previous
//
#include <hip/hip_runtime.h>
#include <stdint.h>

// E=512, H=8, D=64, B=4, Nq=Nk=2048
// bf16 MFMA pipeline: cvt -> QKV proj GEMM (z-batched, Q pre-scaled) -> flash attn
// (8-wave block, 16 q/wave, LDS K/V dbuf, swapped QK^T 16x16, in-register softmax
//  AND P, mask as MFMA C-init, XCD pinning) -> out proj GEMM

typedef __attribute__((ext_vector_type(8))) short bf16x8;  // 8 bf16 in 4 VGPRs
typedef __attribute__((ext_vector_type(4))) float f32x4;

#define SCLQ 0.18033688011112042f  // 0.125 * log2(e): logits emerge in log2 domain

static __device__ __forceinline__ unsigned short f2bf(float f) {
    union { float f; unsigned u; } x; x.f = f;
    unsigned r = x.u + 0x7fffu + ((x.u >> 16) & 1u);  // RTN-even
    return (unsigned short)(r >> 16);
}

static __device__ __forceinline__ f32x4 mfma16(bf16x8 a, bf16x8 b, f32x4 c) {
    return __builtin_amdgcn_mfma_f32_16x16x32_bf16(a, b, c, 0, 0, 0);
}

#define GLOAD_LDS16(g, l)                                                            \
    __builtin_amdgcn_global_load_lds((const __attribute__((address_space(1))) void*)(g), \
                                     (__attribute__((address_space(3))) void*)(l), 16, 0, 0)

// ---------------- conversion kernels ----------------

__global__ __launch_bounds__(256) void cvt_x_kernel(
    const float* __restrict__ xq, const float* __restrict__ xk, const float* __restrict__ xv,
    short* __restrict__ oq, short* __restrict__ ok, short* __restrict__ ov)
{
    const float* src = (blockIdx.y == 0) ? xq : (blockIdx.y == 1) ? xk : xv;
    short* dst = (blockIdx.y == 0) ? oq : (blockIdx.y == 1) ? ok : ov;
    size_t i = (size_t)blockIdx.x * 256 + threadIdx.x;
    float4 v = ((const float4*)src)[i];
    short4 o;
    o.x = (short)f2bf(v.x); o.y = (short)f2bf(v.y);
    o.z = (short)f2bf(v.z); o.w = (short)f2bf(v.w);
    ((short4*)dst)[i] = o;
}

__global__ __launch_bounds__(256) void cvt_wt_kernel(
    const float* __restrict__ Wq, const float* __restrict__ Wk,
    const float* __restrict__ Wv, const float* __restrict__ Wo,
    short* __restrict__ WqT, short* __restrict__ WkT,
    short* __restrict__ WvT, short* __restrict__ WoT)
{
    int z = blockIdx.y;
    const float* W = (z == 0) ? Wq : (z == 1) ? Wk : (z == 2) ? Wv : Wo;
    short* WT = (z == 0) ? WqT : (z == 1) ? WkT : (z == 2) ? WvT : WoT;
    int t = blockIdx.x * 256 + threadIdx.x;
    int n = t & 511;
    int k0 = (t >> 9) * 8;
    union { short s[8]; int4 v; } u;
#pragma unroll
    for (int j = 0; j < 8; ++j) u.s[j] = (short)f2bf(W[(size_t)(k0 + j) * 512 + n]);
    *(int4*)(WT + (size_t)n * 512 + k0) = u.v;
}

// mask (4-byte elems, nonzero = keep) -> packed bits; word w covers k=[w*64,w*64+64)
__global__ __launch_bounds__(256) void pack_mask_kernel(
    const int* __restrict__ mask, unsigned long long* __restrict__ mp)
{
    int lane = threadIdx.x & 63;
    int row = blockIdx.x * 4 + (threadIdx.x >> 6);  // b*2048+q
    const int* mrow = mask + (size_t)row * 2048;
#pragma unroll 4
    for (int w = 0; w < 32; ++w) {
        unsigned long long bits = __ballot(mrow[w * 64 + lane] != 0);
        if (lane == 0) mp[(size_t)row * 32 + w] = bits;
    }
}

// ---------------- GEMM body: C[8192x512] = A[8192x512] @ W (+bias) ----------------
// mode 0: Q -> [b,h,tok,d] bf16, pre-scaled ; 1: K -> [b,h,tok,d] ; 2: V -> [b,h,d,tok]
// mode 3: fp32 row-major out
static __device__ __forceinline__ void gemm_body(
    const short* __restrict__ A, const short* __restrict__ BT,
    const float* __restrict__ bias, void* __restrict__ Cout, int mode,
    char* lds, int bx, int by)
{
    const int tid = threadIdx.x;
    const int lane = tid & 63;
    const int wid = tid >> 6;
    const int l15 = lane & 15, l4 = lane >> 4;
    const int m0 = by * 128;
    const int n0 = bx * 128;
    const int wr = wid >> 1, wc = wid & 1;

    f32x4 zero = {0.f, 0.f, 0.f, 0.f};
    f32x4 acc[4][4];
#pragma unroll
    for (int i = 0; i < 4; ++i)
#pragma unroll
        for (int j = 0; j < 4; ++j) acc[i][j] = zero;

    char* Alds = lds;
    char* Blds = lds + 16384;

    for (int t = 0; t < 8; ++t) {
        const int k0 = t * 64;
#pragma unroll
        for (int s = 0; s < 4; ++s) {
            int p = s * 256 + tid;
            int r = p >> 3, c = p & 7;
            GLOAD_LDS16(A + (size_t)(m0 + r) * 512 + k0 + 8 * (c ^ (r & 7)),
                        Alds + s * 4096 + wid * 1024);
            GLOAD_LDS16(BT + (size_t)(n0 + r) * 512 + k0 + 8 * (c ^ (r & 7)),
                        Blds + s * 4096 + wid * 1024);
        }
        __syncthreads();
#pragma unroll
        for (int ks = 0; ks < 2; ++ks) {
            bf16x8 af[4], bfr[4];
#pragma unroll
            for (int mb = 0; mb < 4; ++mb) {
                int row = wr * 64 + mb * 16 + l15;
                af[mb] = *(const bf16x8*)(Alds + row * 128 +
                                          ((ks * 64 + l4 * 16) ^ ((row & 7) << 4)));
            }
#pragma unroll
            for (int nb = 0; nb < 4; ++nb) {
                int row = wc * 64 + nb * 16 + l15;
                bfr[nb] = *(const bf16x8*)(Blds + row * 128 +
                                           ((ks * 64 + l4 * 16) ^ ((row & 7) << 4)));
            }
#pragma unroll
            for (int mb = 0; mb < 4; ++mb)
#pragma unroll
                for (int nb = 0; nb < 4; ++nb)
                    acc[mb][nb] = mfma16(af[mb], bfr[nb], acc[mb][nb]);
        }
        __syncthreads();
    }

#pragma unroll
    for (int nb = 0; nb < 4; ++nb) {
        int n = n0 + wc * 64 + nb * 16 + l15;
        float bv = bias[n];
#pragma unroll
        for (int mb = 0; mb < 4; ++mb) {
#pragma unroll
            for (int r = 0; r < 4; ++r) {
                int m = m0 + wr * 64 + mb * 16 + l4 * 4 + r;
                float val = acc[mb][nb][r] + bv;
                if (mode == 0) val *= SCLQ;  // fold softmax scale+log2e into Q
                if (mode == 3) {
                    ((float*)Cout)[(size_t)m * 512 + n] = val;
                } else {
                    int b = m >> 11, tok = m & 2047;
                    int h = n >> 6, d = n & 63;
                    short* o = (short*)Cout;
                    if (mode == 2)
                        o[((size_t)(b * 8 + h) * 64 + d) * 2048 + tok] = (short)f2bf(val);
                    else
                        o[((size_t)(b * 8 + h) * 2048 + tok) * 64 + d] = (short)f2bf(val);
                }
            }
        }
    }
}

// z-batched QKV projection: blockIdx.z selects {Q,K,V}
__global__ __launch_bounds__(256) void gemm_qkv_kernel(
    const short* __restrict__ Xq, const short* __restrict__ Xk, const short* __restrict__ Xv,
    const short* __restrict__ WqT, const short* __restrict__ WkT, const short* __restrict__ WvT,
    const float* __restrict__ bq, const float* __restrict__ bk, const float* __restrict__ bv,
    short* __restrict__ Qw, short* __restrict__ Kw, short* __restrict__ VTw)
{
    __shared__ char lds[32768];
    int z = blockIdx.z;
    const short* A = (z == 0) ? Xq : (z == 1) ? Xk : Xv;
    const short* BT = (z == 0) ? WqT : (z == 1) ? WkT : WvT;
    const float* bias = (z == 0) ? bq : (z == 1) ? bk : bv;
    void* Cout = (z == 0) ? (void*)Qw : (z == 1) ? (void*)Kw : (void*)VTw;
    gemm_body(A, BT, bias, Cout, z, lds, blockIdx.x, blockIdx.y);
}

__global__ __launch_bounds__(256) void gemm_kernel(
    const short* __restrict__ A, const short* __restrict__ BT,
    const float* __restrict__ bias, void* __restrict__ Cout, int mode)
{
    __shared__ char lds[32768];
    gemm_body(A, BT, bias, Cout, mode, lds, blockIdx.x, blockIdx.y);
}

// ---------------- masked flash attention: 8-wave, 16 q/wave, in-register P ----------------
// grid 512 = 8 XCD x 4 bh x 16 q-chunks of 128 (xcd = lid&7 pins bh to one XCD's L2).
// Block: 512 thr = 8 waves; wave owns 16 q; KVBLK=64 shared in LDS (global_load_lds w=16,
// dbuf, XOR-swizzled via pre-swizzled global source — R7-verbatim staging).
// Swapped QK^T (verified 16x16 layouts): S^T col=l15=q, row=l4*4+r=k (per 16-token block).
// In-lane tree max + 2 shfl_xor merges; in-register P via sigma16(l4,j)=l4*4+(j&3)+16*(j>>2):
// A-frags = in-order cvt_pk packs of own regs; V B-frags = two ds_read_b64 at matching
// sigma16 offsets. Mask as MFMA C-init. Defer-max THR=8.
__global__ __launch_bounds__(512) void attn_kernel(
    const short* __restrict__ Q, const short* __restrict__ K,
    const short* __restrict__ VT, const unsigned long long* __restrict__ mp,
    short* __restrict__ AO)
{
    __shared__ char lds[32768];  // K dbuf 2x8KB @0; V dbuf 2x8KB @16384
    const int tid = threadIdx.x;
    const int lane = tid & 63;
    const int wid = tid >> 6;
    const int l15 = lane & 15, l4 = lane >> 4;
    const int lid = blockIdx.x;
    const int xcd = lid & 7, jj = lid >> 3;
    const int bhi = (xcd << 2) | (jj >> 4);
    const int b = bhi >> 3, h = bhi & 7;
    const int q0 = (jj & 15) * 128 + wid * 16;
    const short* Qp = Q + ((size_t)bhi * 2048 + q0) * 64;
    const short* Kp = K + (size_t)bhi * 2048 * 64;
    const short* Vp = VT + (size_t)bhi * 64 * 2048;

    // staging map (R7-verbatim): thread t -> row t>>3 (64 rows), 16B chunk t&7,
    // pre-swizzled global source
    const int srow = tid >> 3;
    const int sgo = 8 * ((tid & 7) ^ (srow & 7));
    const int swl = l15 & 7;  // read-side swizzle key (row & 7)

    // Q B-frags: qb[dc] = Q[q0+l15][dc*32+l4*8+j]
    bf16x8 qb[2];
#pragma unroll
    for (int dc = 0; dc < 2; ++dc)
        qb[dc] = *(const bf16x8*)(Qp + l15 * 64 + dc * 32 + l4 * 8);

    const f32x4 zero = {0.f, 0.f, 0.f, 0.f};
    f32x4 o[4];  // o[dt]: q = l4*4 + r, d = dt*16 + l15
#pragma unroll
    for (int dt = 0; dt < 4; ++dt) o[dt] = zero;
    float mrun = -1e30f, lrun = 0.f;

    const unsigned long long* mr0 = mp + ((size_t)b * 2048 + q0 + l15) * 32;

    // prologue: stage tile 0 into buf 0 (R7-verbatim)
    GLOAD_LDS16(Kp + (size_t)srow * 64 + sgo, lds + wid * 1024);
    GLOAD_LDS16(Vp + (size_t)srow * 2048 + sgo, lds + 16384 + wid * 1024);
    unsigned long long mw0 = mr0[0];
    __syncthreads();

    for (int kt = 0; kt < 32; ++kt) {
        const int cur = kt & 1;
        char* Kc = lds + cur * 8192;
        char* Vc = lds + 16384 + cur * 8192;
        if (kt < 31) {  // stage next tile into other buffer
            GLOAD_LDS16(Kp + ((size_t)(kt + 1) * 64 + srow) * 64 + sgo,
                        lds + (cur ^ 1) * 8192 + wid * 1024);
            GLOAD_LDS16(Vp + (size_t)srow * 2048 + (kt + 1) * 64 + sgo,
                        lds + 16384 + (cur ^ 1) * 8192 + wid * 1024);
        }
        unsigned long long mn0 = (kt < 31) ? mr0[kt + 1] : 0ull;

        // K A-frags: row = tb*16+l15 (token), d = dc*32+l4*8+j
        bf16x8 ka[4][2];
#pragma unroll
        for (int tb = 0; tb < 4; ++tb)
#pragma unroll
            for (int dc = 0; dc < 2; ++dc)
                ka[tb][dc] = *(const bf16x8*)(Kc + (tb * 16 + l15) * 128 +
                                              16 * ((dc * 4 + l4) ^ swl));

        // QK^T with mask C-init: sv[tb][r] = S^T[token tb*16+l4*4+r][q] + (bit?0:-1e30)
        f32x4 sv[4];
#pragma unroll
        for (int tb = 0; tb < 4; ++tb) {
            unsigned u0 = (unsigned)(mw0 >> (tb * 16 + l4 * 4));
            f32x4 i0;
#pragma unroll
            for (int r = 0; r < 4; ++r)
                i0[r] = (u0 & (1u << r)) ? 0.f : -1e30f;
            sv[tb] = mfma16(ka[tb][1], qb[1], mfma16(ka[tb][0], qb[0], i0));
        }

        // V B-frags at sigma16 offsets
        bf16x8 vb[4][2];
#pragma unroll
        for (int dt = 0; dt < 4; ++dt)
#pragma unroll
            for (int kb = 0; kb < 2; ++kb) {
                const char* vr = Vc + (dt * 16 + l15) * 128;
                uint2 x = *(const uint2*)(vr + 16 * ((kb * 4 + (l4 >> 1)) ^ swl) +
                                          (l4 & 1) * 8);
                uint2 y = *(const uint2*)(vr + 16 * ((kb * 4 + 2 + (l4 >> 1)) ^ swl) +
                                          (l4 & 1) * 8);
                uint4 t; t.x = x.x; t.y = x.y; t.z = y.x; t.w = y.y;
                vb[dt][kb] = *(bf16x8*)&t;
            }

        // in-lane tree max (depth 4) + 2 shfl_xor merges
        f32x4 m0v;
#pragma unroll
        for (int r = 0; r < 4; ++r)
            m0v[r] = fmaxf(fmaxf(sv[0][r], sv[1][r]), fmaxf(sv[2][r], sv[3][r]));
        float pm0 = fmaxf(fmaxf(m0v[0], m0v[1]), fmaxf(m0v[2], m0v[3]));
        pm0 = fmaxf(pm0, __shfl_xor(pm0, 16, 64));
        pm0 = fmaxf(pm0, __shfl_xor(pm0, 32, 64));

        // defer-max (T13): rescale only when the row max grew past THR=8 (log2 units)
        if (__any(pm0 > mrun + 8.f)) {
            float mnew = fmaxf(mrun, pm0);
            float al = exp2f(mrun - mnew);
            mrun = mnew; lrun *= al;
#pragma unroll
            for (int r = 0; r < 4; ++r) {
                float alr = __shfl(al, l4 * 4 + r, 64);
#pragma unroll
                for (int dt = 0; dt < 4; ++dt) o[dt][r] *= alr;
            }
        }

        // exp2 in place + per-lane partial sums (lane's 16 tokens; merged at epilogue)
#pragma unroll
        for (int tb = 0; tb < 4; ++tb)
#pragma unroll
            for (int r = 0; r < 4; ++r)
                sv[tb][r] = exp2f(sv[tb][r] - mrun);
        {
            f32x4 t0 = (sv[0] + sv[1]) + (sv[2] + sv[3]);
            lrun += (t0[0] + t0[1]) + (t0[2] + t0[3]);
        }

        // pack P A-frags: pa[kb] = in-order cvt_pk of own regs (sigma16-matched)
        bf16x8 pa[2];
#define PACK8(DST, SA, SB)                                                              \
        { uint4 t_;                                                                     \
          asm("v_cvt_pk_bf16_f32 %0, %1, %2" : "=v"(t_.x) : "v"(SA[0]), "v"(SA[1]));    \
          asm("v_cvt_pk_bf16_f32 %0, %1, %2" : "=v"(t_.y) : "v"(SA[2]), "v"(SA[3]));    \
          asm("v_cvt_pk_bf16_f32 %0, %1, %2" : "=v"(t_.z) : "v"(SB[0]), "v"(SB[1]));    \
          asm("v_cvt_pk_bf16_f32 %0, %1, %2" : "=v"(t_.w) : "v"(SB[2]), "v"(SB[3]));    \
          DST = *(bf16x8*)&t_; }
        PACK8(pa[0], sv[0], sv[1])
        PACK8(pa[1], sv[2], sv[3])
#undef PACK8

        // PV: o[dt] += P(kb) x V(kb), contraction over 2 x 32 tokens
#pragma unroll
        for (int dt = 0; dt < 4; ++dt)
            o[dt] = mfma16(pa[1], vb[dt][1], mfma16(pa[0], vb[dt][0], o[dt]));

        mw0 = mn0;
        __syncthreads();  // drains stage loads + LDS reads; swap buffers
    }

    // epilogue: merge l4-group partial sums, normalize, store
    {
        float lt = lrun;
        lt += __shfl_xor(lt, 16, 64);
        lt += __shfl_xor(lt, 32, 64);
        float inv = 1.0f / lt;  // for q = q0 + l15
#pragma unroll
        for (int r = 0; r < 4; ++r) {
            float invr = __shfl(inv, l4 * 4 + r, 64);
            size_t base = ((size_t)b * 2048 + q0 + l4 * 4 + r) * 512 + h * 64;
#pragma unroll
            for (int dt = 0; dt < 4; ++dt)
                AO[base + dt * 16 + l15] = (short)f2bf(o[dt][r] * invr);
        }
    }
}

// ---------------- launcher ----------------
extern "C" void kernel_launch(void* const* d_in, const int* in_sizes, int n_in,
                              void* d_out, int out_size, void* d_ws, size_t ws_size,
                              hipStream_t stream) {
    const float* q  = (const float*)d_in[0];
    const float* k  = (const float*)d_in[1];
    const float* v  = (const float*)d_in[2];
    const int*   gm = (const int*)d_in[3];
    const float* Wq = (const float*)d_in[4];  const float* bq = (const float*)d_in[5];
    const float* Wk = (const float*)d_in[6];  const float* bk = (const float*)d_in[7];
    const float* Wv = (const float*)d_in[8];  const float* bv = (const float*)d_in[9];
    const float* Wo = (const float*)d_in[10]; const float* bo = (const float*)d_in[11];

    char* ws = (char*)d_ws;
    short* Xq  = (short*)(ws + 0);
    short* Xk  = (short*)(ws + 8388608);
    short* Xv  = (short*)(ws + 16777216);
    short* WqT = (short*)(ws + 25165824);
    short* WkT = (short*)(ws + 25690112);
    short* WvT = (short*)(ws + 26214400);
    short* WoT = (short*)(ws + 26738688);
    short* Qw  = (short*)(ws + 27262976);    // [b,h,tok,d] (pre-scaled)
    short* Kw  = (short*)(ws + 35651584);    // [b,h,tok,d]
    short* VTw = (short*)(ws + 44040192);    // [b,h,d,tok]
    short* AO  = (short*)(ws + 52428800);    // attn out [b,tok,h*64+d]
    unsigned long long* MP = (unsigned long long*)(ws + 60817408);

    cvt_x_kernel<<<dim3(4096, 3), 256, 0, stream>>>(q, k, v, Xq, Xk, Xv);
    cvt_wt_kernel<<<dim3(128, 4), 256, 0, stream>>>(Wq, Wk, Wv, Wo, WqT, WkT, WvT, WoT);
    pack_mask_kernel<<<dim3(2048), 256, 0, stream>>>(gm, MP);

    gemm_qkv_kernel<<<dim3(4, 64, 3), 256, 0, stream>>>(Xq, Xk, Xv, WqT, WkT, WvT,
                                                        bq, bk, bv, Qw, Kw, VTw);

    attn_kernel<<<dim3(512), 512, 0, stream>>>(Qw, Kw, VTw, MP, AO);

    gemm_kernel<<<dim3(4, 64), 256, 0, stream>>>(AO, WoT, bo, (void*)d_out, 3);
}

// Round 10
// 165.988 us; speedup vs baseline: 2.1910x; 1.0140x over previous
//
#include <hip/hip_runtime.h>
#include <stdint.h>

// E=512, H=8, D=64, B=4, Nq=Nk=2048
// bf16 MFMA pipeline: cvt -> QKV proj GEMM (z-batched, Q pre-scaled) -> flash attn
// (8-wave block, 16 q/wave, LDS K/V dbuf, swapped QK^T 16x16, in-register softmax
//  AND P, mask+running-max-bias as MFMA C-init, deferred max merge, XCD pinning)
// -> out proj GEMM

typedef __attribute__((ext_vector_type(8))) short bf16x8;  // 8 bf16 in 4 VGPRs
typedef __attribute__((ext_vector_type(4))) float f32x4;

#define SCLQ 0.18033688011112042f  // 0.125 * log2(e): logits emerge in log2 domain

static __device__ __forceinline__ unsigned short f2bf(float f) {
    union { float f; unsigned u; } x; x.f = f;
    unsigned r = x.u + 0x7fffu + ((x.u >> 16) & 1u);  // RTN-even
    return (unsigned short)(r >> 16);
}

static __device__ __forceinline__ f32x4 mfma16(bf16x8 a, bf16x8 b, f32x4 c) {
    return __builtin_amdgcn_mfma_f32_16x16x32_bf16(a, b, c, 0, 0, 0);
}

#define GLOAD_LDS16(g, l)                                                            \
    __builtin_amdgcn_global_load_lds((const __attribute__((address_space(1))) void*)(g), \
                                     (__attribute__((address_space(3))) void*)(l), 16, 0, 0)

// ---------------- conversion kernels ----------------

__global__ __launch_bounds__(256) void cvt_x_kernel(
    const float* __restrict__ xq, const float* __restrict__ xk, const float* __restrict__ xv,
    short* __restrict__ oq, short* __restrict__ ok, short* __restrict__ ov)
{
    const float* src = (blockIdx.y == 0) ? xq : (blockIdx.y == 1) ? xk : xv;
    short* dst = (blockIdx.y == 0) ? oq : (blockIdx.y == 1) ? ok : ov;
    size_t i = (size_t)blockIdx.x * 256 + threadIdx.x;
    float4 v = ((const float4*)src)[i];
    short4 o;
    o.x = (short)f2bf(v.x); o.y = (short)f2bf(v.y);
    o.z = (short)f2bf(v.z); o.w = (short)f2bf(v.w);
    ((short4*)dst)[i] = o;
}

__global__ __launch_bounds__(256) void cvt_wt_kernel(
    const float* __restrict__ Wq, const float* __restrict__ Wk,
    const float* __restrict__ Wv, const float* __restrict__ Wo,
    short* __restrict__ WqT, short* __restrict__ WkT,
    short* __restrict__ WvT, short* __restrict__ WoT)
{
    int z = blockIdx.y;
    const float* W = (z == 0) ? Wq : (z == 1) ? Wk : (z == 2) ? Wv : Wo;
    short* WT = (z == 0) ? WqT : (z == 1) ? WkT : (z == 2) ? WvT : WoT;
    int t = blockIdx.x * 256 + threadIdx.x;
    int n = t & 511;
    int k0 = (t >> 9) * 8;
    union { short s[8]; int4 v; } u;
#pragma unroll
    for (int j = 0; j < 8; ++j) u.s[j] = (short)f2bf(W[(size_t)(k0 + j) * 512 + n]);
    *(int4*)(WT + (size_t)n * 512 + k0) = u.v;
}

// mask (4-byte elems, nonzero = keep) -> packed bits; word w covers k=[w*64,w*64+64)
__global__ __launch_bounds__(256) void pack_mask_kernel(
    const int* __restrict__ mask, unsigned long long* __restrict__ mp)
{
    int lane = threadIdx.x & 63;
    int row = blockIdx.x * 4 + (threadIdx.x >> 6);  // b*2048+q
    const int* mrow = mask + (size_t)row * 2048;
#pragma unroll 4
    for (int w = 0; w < 32; ++w) {
        unsigned long long bits = __ballot(mrow[w * 64 + lane] != 0);
        if (lane == 0) mp[(size_t)row * 32 + w] = bits;
    }
}

// ---------------- GEMM body: C[8192x512] = A[8192x512] @ W (+bias) ----------------
// mode 0: Q -> [b,h,tok,d] bf16, pre-scaled ; 1: K -> [b,h,tok,d] ; 2: V -> [b,h,d,tok]
// mode 3: fp32 row-major out
static __device__ __forceinline__ void gemm_body(
    const short* __restrict__ A, const short* __restrict__ BT,
    const float* __restrict__ bias, void* __restrict__ Cout, int mode,
    char* lds, int bx, int by)
{
    const int tid = threadIdx.x;
    const int lane = tid & 63;
    const int wid = tid >> 6;
    const int l15 = lane & 15, l4 = lane >> 4;
    const int m0 = by * 128;
    const int n0 = bx * 128;
    const int wr = wid >> 1, wc = wid & 1;

    f32x4 zero = {0.f, 0.f, 0.f, 0.f};
    f32x4 acc[4][4];
#pragma unroll
    for (int i = 0; i < 4; ++i)
#pragma unroll
        for (int j = 0; j < 4; ++j) acc[i][j] = zero;

    char* Alds = lds;
    char* Blds = lds + 16384;

    for (int t = 0; t < 8; ++t) {
        const int k0 = t * 64;
#pragma unroll
        for (int s = 0; s < 4; ++s) {
            int p = s * 256 + tid;
            int r = p >> 3, c = p & 7;
            GLOAD_LDS16(A + (size_t)(m0 + r) * 512 + k0 + 8 * (c ^ (r & 7)),
                        Alds + s * 4096 + wid * 1024);
            GLOAD_LDS16(BT + (size_t)(n0 + r) * 512 + k0 + 8 * (c ^ (r & 7)),
                        Blds + s * 4096 + wid * 1024);
        }
        __syncthreads();
#pragma unroll
        for (int ks = 0; ks < 2; ++ks) {
            bf16x8 af[4], bfr[4];
#pragma unroll
            for (int mb = 0; mb < 4; ++mb) {
                int row = wr * 64 + mb * 16 + l15;
                af[mb] = *(const bf16x8*)(Alds + row * 128 +
                                          ((ks * 64 + l4 * 16) ^ ((row & 7) << 4)));
            }
#pragma unroll
            for (int nb = 0; nb < 4; ++nb) {
                int row = wc * 64 + nb * 16 + l15;
                bfr[nb] = *(const bf16x8*)(Blds + row * 128 +
                                           ((ks * 64 + l4 * 16) ^ ((row & 7) << 4)));
            }
#pragma unroll
            for (int mb = 0; mb < 4; ++mb)
#pragma unroll
                for (int nb = 0; nb < 4; ++nb)
                    acc[mb][nb] = mfma16(af[mb], bfr[nb], acc[mb][nb]);
        }
        __syncthreads();
    }

#pragma unroll
    for (int nb = 0; nb < 4; ++nb) {
        int n = n0 + wc * 64 + nb * 16 + l15;
        float bv = bias[n];
#pragma unroll
        for (int mb = 0; mb < 4; ++mb) {
#pragma unroll
            for (int r = 0; r < 4; ++r) {
                int m = m0 + wr * 64 + mb * 16 + l4 * 4 + r;
                float val = acc[mb][nb][r] + bv;
                if (mode == 0) val *= SCLQ;  // fold softmax scale+log2e into Q
                if (mode == 3) {
                    ((float*)Cout)[(size_t)m * 512 + n] = val;
                } else {
                    int b = m >> 11, tok = m & 2047;
                    int h = n >> 6, d = n & 63;
                    short* o = (short*)Cout;
                    if (mode == 2)
                        o[((size_t)(b * 8 + h) * 64 + d) * 2048 + tok] = (short)f2bf(val);
                    else
                        o[((size_t)(b * 8 + h) * 2048 + tok) * 64 + d] = (short)f2bf(val);
                }
            }
        }
    }
}

// z-batched QKV projection: blockIdx.z selects {Q,K,V}
__global__ __launch_bounds__(256) void gemm_qkv_kernel(
    const short* __restrict__ Xq, const short* __restrict__ Xk, const short* __restrict__ Xv,
    const short* __restrict__ WqT, const short* __restrict__ WkT, const short* __restrict__ WvT,
    const float* __restrict__ bq, const float* __restrict__ bk, const float* __restrict__ bv,
    short* __restrict__ Qw, short* __restrict__ Kw, short* __restrict__ VTw)
{
    __shared__ char lds[32768];
    int z = blockIdx.z;
    const short* A = (z == 0) ? Xq : (z == 1) ? Xk : Xv;
    const short* BT = (z == 0) ? WqT : (z == 1) ? WkT : WvT;
    const float* bias = (z == 0) ? bq : (z == 1) ? bk : bv;
    void* Cout = (z == 0) ? (void*)Qw : (z == 1) ? (void*)Kw : (void*)VTw;
    gemm_body(A, BT, bias, Cout, z, lds, blockIdx.x, blockIdx.y);
}

__global__ __launch_bounds__(256) void gemm_kernel(
    const short* __restrict__ A, const short* __restrict__ BT,
    const float* __restrict__ bias, void* __restrict__ Cout, int mode)
{
    __shared__ char lds[32768];
    gemm_body(A, BT, bias, Cout, mode, lds, blockIdx.x, blockIdx.y);
}

// ---------------- masked flash attention: 8-wave, 16 q/wave, in-register P ----------------
// grid 512 = 8 XCD x 4 bh x 16 q-chunks of 128 (xcd = lid&7 pins bh to one XCD's L2).
// Block: 512 thr = 8 waves; wave owns 16 q; KVBLK=64 shared in LDS (global_load_lds w=16,
// dbuf, XOR-swizzled via pre-swizzled global source — R7/R9-verbatim staging).
// Swapped QK^T (verified 16x16 layouts): S^T col=l15=q, row=l4*4+r=k (per 16-token block).
// NEW vs R9: C-init = bit ? -mrun : -1e30 so QK^T emits s-mrun directly (exp2 needs no
// sub); deferred max MERGE — common path is in-lane max3 tree + cmp-to-8 + __any; the
// 2 shfl_xor row-merges + rescale + sv re-bias run only on violation (rare, T13).
// In-register P via sigma16; V B-frags = two ds_read_b64 at matching sigma16 offsets.
__global__ __launch_bounds__(512) void attn_kernel(
    const short* __restrict__ Q, const short* __restrict__ K,
    const short* __restrict__ VT, const unsigned long long* __restrict__ mp,
    short* __restrict__ AO)
{
    __shared__ char lds[32768];  // K dbuf 2x8KB @0; V dbuf 2x8KB @16384
    const int tid = threadIdx.x;
    const int lane = tid & 63;
    const int wid = tid >> 6;
    const int l15 = lane & 15, l4 = lane >> 4;
    const int lid = blockIdx.x;
    const int xcd = lid & 7, jj = lid >> 3;
    const int bhi = (xcd << 2) | (jj >> 4);
    const int b = bhi >> 3, h = bhi & 7;
    const int q0 = (jj & 15) * 128 + wid * 16;
    const short* Qp = Q + ((size_t)bhi * 2048 + q0) * 64;
    const short* Kp = K + (size_t)bhi * 2048 * 64;
    const short* Vp = VT + (size_t)bhi * 64 * 2048;

    // staging map (R9-verbatim): thread t -> row t>>3, 16B chunk t&7, pre-swizzled source
    const int srow = tid >> 3;
    const int sgo = 8 * ((tid & 7) ^ (srow & 7));
    const int swl = l15 & 7;  // read-side swizzle key (row & 7)

    // Q B-frags: qb[dc] = Q[q0+l15][dc*32+l4*8+j]
    bf16x8 qb[2];
#pragma unroll
    for (int dc = 0; dc < 2; ++dc)
        qb[dc] = *(const bf16x8*)(Qp + l15 * 64 + dc * 32 + l4 * 8);

    const f32x4 zero = {0.f, 0.f, 0.f, 0.f};
    f32x4 o[4];  // o[dt]: q = l4*4 + r, d = dt*16 + l15
#pragma unroll
    for (int dt = 0; dt < 4; ++dt) o[dt] = zero;
    // running max starts at 0 (logits are ~N(0,few) in log2 domain); violation
    // mechanism raises it if any tile max exceeds mrun+8. lrun accumulates
    // exp2(s - mrun); P bounded by 2^8 between violations (bf16-safe, f32 accum).
    float mrun = 0.f, lrun = 0.f;

    const unsigned long long* mr0 = mp + ((size_t)b * 2048 + q0 + l15) * 32;

    // prologue: stage tile 0 into buf 0 (R9-verbatim)
    GLOAD_LDS16(Kp + (size_t)srow * 64 + sgo, lds + wid * 1024);
    GLOAD_LDS16(Vp + (size_t)srow * 2048 + sgo, lds + 16384 + wid * 1024);
    unsigned long long mw0 = mr0[0];
    __syncthreads();

    for (int kt = 0; kt < 32; ++kt) {
        const int cur = kt & 1;
        char* Kc = lds + cur * 8192;
        char* Vc = lds + 16384 + cur * 8192;
        if (kt < 31) {  // stage next tile into other buffer
            GLOAD_LDS16(Kp + ((size_t)(kt + 1) * 64 + srow) * 64 + sgo,
                        lds + (cur ^ 1) * 8192 + wid * 1024);
            GLOAD_LDS16(Vp + (size_t)srow * 2048 + (kt + 1) * 64 + sgo,
                        lds + 16384 + (cur ^ 1) * 8192 + wid * 1024);
        }
        unsigned long long mn0 = (kt < 31) ? mr0[kt + 1] : 0ull;

        // K A-frags: row = tb*16+l15 (token), d = dc*32+l4*8+j
        bf16x8 ka[4][2];
#pragma unroll
        for (int tb = 0; tb < 4; ++tb)
#pragma unroll
            for (int dc = 0; dc < 2; ++dc)
                ka[tb][dc] = *(const bf16x8*)(Kc + (tb * 16 + l15) * 128 +
                                              16 * ((dc * 4 + l4) ^ swl));

        // V B-frags at sigma16 offsets (hoisted BEFORE QK^T MFMAs: independent reads)
        bf16x8 vb[4][2];
#pragma unroll
        for (int dt = 0; dt < 4; ++dt)
#pragma unroll
            for (int kb = 0; kb < 2; ++kb) {
                const char* vr = Vc + (dt * 16 + l15) * 128;
                uint2 x = *(const uint2*)(vr + 16 * ((kb * 4 + (l4 >> 1)) ^ swl) +
                                          (l4 & 1) * 8);
                uint2 y = *(const uint2*)(vr + 16 * ((kb * 4 + 2 + (l4 >> 1)) ^ swl) +
                                          (l4 & 1) * 8);
                uint4 t; t.x = x.x; t.y = x.y; t.z = y.x; t.w = y.y;
                vb[dt][kb] = *(bf16x8*)&t;
            }

        // QK^T with bias+mask C-init: sv = (s - mrun) unmasked, ~-1e30 masked.
        // One 64-bit shift; bit (tb*16+r) of u selects per element.
        const float nm = -mrun;
        unsigned long long u64 = mw0 >> (l4 * 4);
        unsigned ulo = (unsigned)u64, uhi = (unsigned)(u64 >> 32);
        f32x4 sv[4];
#pragma unroll
        for (int tb = 0; tb < 4; ++tb) {
            unsigned us = (tb & 2) ? uhi : ulo;
            f32x4 i0;
#pragma unroll
            for (int r = 0; r < 4; ++r)
                i0[r] = (us & (1u << (((tb & 1) << 4) + r))) ? nm : -1e30f;
            sv[tb] = mfma16(ka[tb][1], qb[1], mfma16(ka[tb][0], qb[0], i0));
        }

        // in-lane max tree (fmax chains fuse to v_max3), compare to constant THR=8
        float pml;
        {
            f32x4 m0v;
#pragma unroll
            for (int r = 0; r < 4; ++r)
                m0v[r] = fmaxf(fmaxf(sv[0][r], sv[1][r]), fmaxf(sv[2][r], sv[3][r]));
            pml = fmaxf(fmaxf(m0v[0], m0v[1]), fmaxf(m0v[2], m0v[3]));
        }
        // deferred merge: only on violation do the row-merge shfls + rescale + re-bias
        if (__any(pml > 8.f)) {
            float pm = fmaxf(pml, __shfl_xor(pml, 16, 64));
            pm = fmaxf(pm, __shfl_xor(pm, 32, 64));   // row max of (s - mrun_old)
            float dm = fmaxf(pm, 0.f);                 // mnew - mold >= 0
            float al = exp2f(-dm);
            mrun += dm;
            lrun *= al;
#pragma unroll
            for (int r = 0; r < 4; ++r) {
                float alr = __shfl(al, l4 * 4 + r, 64);
#pragma unroll
                for (int dt = 0; dt < 4; ++dt) o[dt][r] *= alr;
            }
#pragma unroll
            for (int tb = 0; tb < 4; ++tb)
#pragma unroll
                for (int r = 0; r < 4; ++r) sv[tb][r] -= dm;
        }

        // P = exp2(sv) directly (bias already applied via C-init)
#pragma unroll
        for (int tb = 0; tb < 4; ++tb)
#pragma unroll
            for (int r = 0; r < 4; ++r)
                sv[tb][r] = exp2f(sv[tb][r]);
        {
            f32x4 t0 = (sv[0] + sv[1]) + (sv[2] + sv[3]);
            lrun += (t0[0] + t0[1]) + (t0[2] + t0[3]);
        }

        // pack P A-frags: pa[kb] = in-order cvt_pk of own regs (sigma16-matched)
        bf16x8 pa[2];
#define PACK8(DST, SA, SB)                                                              \
        { uint4 t_;                                                                     \
          asm("v_cvt_pk_bf16_f32 %0, %1, %2" : "=v"(t_.x) : "v"(SA[0]), "v"(SA[1]));    \
          asm("v_cvt_pk_bf16_f32 %0, %1, %2" : "=v"(t_.y) : "v"(SA[2]), "v"(SA[3]));    \
          asm("v_cvt_pk_bf16_f32 %0, %1, %2" : "=v"(t_.z) : "v"(SB[0]), "v"(SB[1]));    \
          asm("v_cvt_pk_bf16_f32 %0, %1, %2" : "=v"(t_.w) : "v"(SB[2]), "v"(SB[3]));    \
          DST = *(bf16x8*)&t_; }
        PACK8(pa[0], sv[0], sv[1])
        PACK8(pa[1], sv[2], sv[3])
#undef PACK8

        // PV: o[dt] += P(kb) x V(kb), contraction over 2 x 32 tokens
#pragma unroll
        for (int dt = 0; dt < 4; ++dt)
            o[dt] = mfma16(pa[1], vb[dt][1], mfma16(pa[0], vb[dt][0], o[dt]));

        mw0 = mn0;
        __syncthreads();  // drains stage loads + LDS reads; swap buffers
    }

    // epilogue: merge l4-group partial sums, normalize, store
    {
        float lt = lrun;
        lt += __shfl_xor(lt, 16, 64);
        lt += __shfl_xor(lt, 32, 64);
        float inv = 1.0f / lt;  // for q = q0 + l15
#pragma unroll
        for (int r = 0; r < 4; ++r) {
            float invr = __shfl(inv, l4 * 4 + r, 64);
            size_t base = ((size_t)b * 2048 + q0 + l4 * 4 + r) * 512 + h * 64;
#pragma unroll
            for (int dt = 0; dt < 4; ++dt)
                AO[base + dt * 16 + l15] = (short)f2bf(o[dt][r] * invr);
        }
    }
}

// ---------------- launcher ----------------
extern "C" void kernel_launch(void* const* d_in, const int* in_sizes, int n_in,
                              void* d_out, int out_size, void* d_ws, size_t ws_size,
                              hipStream_t stream) {
    const float* q  = (const float*)d_in[0];
    const float* k  = (const float*)d_in[1];
    const float* v  = (const float*)d_in[2];
    const int*   gm = (const int*)d_in[3];
    const float* Wq = (const float*)d_in[4];  const float* bq = (const float*)d_in[5];
    const float* Wk = (const float*)d_in[6];  const float* bk = (const float*)d_in[7];
    const float* Wv = (const float*)d_in[8];  const float* bv = (const float*)d_in[9];
    const float* Wo = (const float*)d_in[10]; const float* bo = (const float*)d_in[11];

    char* ws = (char*)d_ws;
    short* Xq  = (short*)(ws + 0);
    short* Xk  = (short*)(ws + 8388608);
    short* Xv  = (short*)(ws + 16777216);
    short* WqT = (short*)(ws + 25165824);
    short* WkT = (short*)(ws + 25690112);
    short* WvT = (short*)(ws + 26214400);
    short* WoT = (short*)(ws + 26738688);
    short* Qw  = (short*)(ws + 27262976);    // [b,h,tok,d] (pre-scaled)
    short* Kw  = (short*)(ws + 35651584);    // [b,h,tok,d]
    short* VTw = (short*)(ws + 44040192);    // [b,h,d,tok]
    short* AO  = (short*)(ws + 52428800);    // attn out [b,tok,h*64+d]
    unsigned long long* MP = (unsigned long long*)(ws + 60817408);

    cvt_x_kernel<<<dim3(4096, 3), 256, 0, stream>>>(q, k, v, Xq, Xk, Xv);
    cvt_wt_kernel<<<dim3(128, 4), 256, 0, stream>>>(Wq, Wk, Wv, Wo, WqT, WkT, WvT, WoT);
    pack_mask_kernel<<<dim3(2048), 256, 0, stream>>>(gm, MP);

    gemm_qkv_kernel<<<dim3(4, 64, 3), 256, 0, stream>>>(Xq, Xk, Xv, WqT, WkT, WvT,
                                                        bq, bk, bv, Qw, Kw, VTw);

    attn_kernel<<<dim3(512), 512, 0, stream>>>(Qw, Kw, VTw, MP, AO);

    gemm_kernel<<<dim3(4, 64), 256, 0, stream>>>(AO, WoT, bo, (void*)d_out, 3);
}

// Round 11
// 165.880 us; speedup vs baseline: 2.1924x; 1.0007x over previous
//
#include <hip/hip_runtime.h>
#include <stdint.h>

// E=512, H=8, D=64, B=4, Nq=Nk=2048
// bf16 MFMA pipeline: cvt -> QKV proj GEMM (z-batched, Q pre-scaled) -> flash attn
// (8-wave block, 16 q/wave, KVBLK=128 staged / one barrier per 128 tokens,
//  LDS K/V dbuf, swapped QK^T 16x16, in-register softmax AND P,
//  mask+running-max-bias as MFMA C-init, deferred max merge, XCD pinning)
// -> out proj GEMM

typedef __attribute__((ext_vector_type(8))) short bf16x8;  // 8 bf16 in 4 VGPRs
typedef __attribute__((ext_vector_type(4))) float f32x4;

#define SCLQ 0.18033688011112042f  // 0.125 * log2(e): logits emerge in log2 domain

static __device__ __forceinline__ unsigned short f2bf(float f) {
    union { float f; unsigned u; } x; x.f = f;
    unsigned r = x.u + 0x7fffu + ((x.u >> 16) & 1u);  // RTN-even
    return (unsigned short)(r >> 16);
}

static __device__ __forceinline__ f32x4 mfma16(bf16x8 a, bf16x8 b, f32x4 c) {
    return __builtin_amdgcn_mfma_f32_16x16x32_bf16(a, b, c, 0, 0, 0);
}

#define GLOAD_LDS16(g, l)                                                            \
    __builtin_amdgcn_global_load_lds((const __attribute__((address_space(1))) void*)(g), \
                                     (__attribute__((address_space(3))) void*)(l), 16, 0, 0)

// ---------------- conversion kernels ----------------

__global__ __launch_bounds__(256) void cvt_x_kernel(
    const float* __restrict__ xq, const float* __restrict__ xk, const float* __restrict__ xv,
    short* __restrict__ oq, short* __restrict__ ok, short* __restrict__ ov)
{
    const float* src = (blockIdx.y == 0) ? xq : (blockIdx.y == 1) ? xk : xv;
    short* dst = (blockIdx.y == 0) ? oq : (blockIdx.y == 1) ? ok : ov;
    size_t i = (size_t)blockIdx.x * 256 + threadIdx.x;
    float4 v = ((const float4*)src)[i];
    short4 o;
    o.x = (short)f2bf(v.x); o.y = (short)f2bf(v.y);
    o.z = (short)f2bf(v.z); o.w = (short)f2bf(v.w);
    ((short4*)dst)[i] = o;
}

__global__ __launch_bounds__(256) void cvt_wt_kernel(
    const float* __restrict__ Wq, const float* __restrict__ Wk,
    const float* __restrict__ Wv, const float* __restrict__ Wo,
    short* __restrict__ WqT, short* __restrict__ WkT,
    short* __restrict__ WvT, short* __restrict__ WoT)
{
    int z = blockIdx.y;
    const float* W = (z == 0) ? Wq : (z == 1) ? Wk : (z == 2) ? Wv : Wo;
    short* WT = (z == 0) ? WqT : (z == 1) ? WkT : (z == 2) ? WvT : WoT;
    int t = blockIdx.x * 256 + threadIdx.x;
    int n = t & 511;
    int k0 = (t >> 9) * 8;
    union { short s[8]; int4 v; } u;
#pragma unroll
    for (int j = 0; j < 8; ++j) u.s[j] = (short)f2bf(W[(size_t)(k0 + j) * 512 + n]);
    *(int4*)(WT + (size_t)n * 512 + k0) = u.v;
}

// mask (4-byte elems, nonzero = keep) -> packed bits; word w covers k=[w*64,w*64+64)
__global__ __launch_bounds__(256) void pack_mask_kernel(
    const int* __restrict__ mask, unsigned long long* __restrict__ mp)
{
    int lane = threadIdx.x & 63;
    int row = blockIdx.x * 4 + (threadIdx.x >> 6);  // b*2048+q
    const int* mrow = mask + (size_t)row * 2048;
#pragma unroll 4
    for (int w = 0; w < 32; ++w) {
        unsigned long long bits = __ballot(mrow[w * 64 + lane] != 0);
        if (lane == 0) mp[(size_t)row * 32 + w] = bits;
    }
}

// ---------------- GEMM body: C[8192x512] = A[8192x512] @ W (+bias) ----------------
// mode 0: Q -> [b,h,tok,d] bf16, pre-scaled ; 1: K -> [b,h,tok,d] ; 2: V -> [b,h,d,tok]
// mode 3: fp32 row-major out
static __device__ __forceinline__ void gemm_body(
    const short* __restrict__ A, const short* __restrict__ BT,
    const float* __restrict__ bias, void* __restrict__ Cout, int mode,
    char* lds, int bx, int by)
{
    const int tid = threadIdx.x;
    const int lane = tid & 63;
    const int wid = tid >> 6;
    const int l15 = lane & 15, l4 = lane >> 4;
    const int m0 = by * 128;
    const int n0 = bx * 128;
    const int wr = wid >> 1, wc = wid & 1;

    f32x4 zero = {0.f, 0.f, 0.f, 0.f};
    f32x4 acc[4][4];
#pragma unroll
    for (int i = 0; i < 4; ++i)
#pragma unroll
        for (int j = 0; j < 4; ++j) acc[i][j] = zero;

    char* Alds = lds;
    char* Blds = lds + 16384;

    for (int t = 0; t < 8; ++t) {
        const int k0 = t * 64;
#pragma unroll
        for (int s = 0; s < 4; ++s) {
            int p = s * 256 + tid;
            int r = p >> 3, c = p & 7;
            GLOAD_LDS16(A + (size_t)(m0 + r) * 512 + k0 + 8 * (c ^ (r & 7)),
                        Alds + s * 4096 + wid * 1024);
            GLOAD_LDS16(BT + (size_t)(n0 + r) * 512 + k0 + 8 * (c ^ (r & 7)),
                        Blds + s * 4096 + wid * 1024);
        }
        __syncthreads();
#pragma unroll
        for (int ks = 0; ks < 2; ++ks) {
            bf16x8 af[4], bfr[4];
#pragma unroll
            for (int mb = 0; mb < 4; ++mb) {
                int row = wr * 64 + mb * 16 + l15;
                af[mb] = *(const bf16x8*)(Alds + row * 128 +
                                          ((ks * 64 + l4 * 16) ^ ((row & 7) << 4)));
            }
#pragma unroll
            for (int nb = 0; nb < 4; ++nb) {
                int row = wc * 64 + nb * 16 + l15;
                bfr[nb] = *(const bf16x8*)(Blds + row * 128 +
                                           ((ks * 64 + l4 * 16) ^ ((row & 7) << 4)));
            }
#pragma unroll
            for (int mb = 0; mb < 4; ++mb)
#pragma unroll
                for (int nb = 0; nb < 4; ++nb)
                    acc[mb][nb] = mfma16(af[mb], bfr[nb], acc[mb][nb]);
        }
        __syncthreads();
    }

#pragma unroll
    for (int nb = 0; nb < 4; ++nb) {
        int n = n0 + wc * 64 + nb * 16 + l15;
        float bv = bias[n];
#pragma unroll
        for (int mb = 0; mb < 4; ++mb) {
#pragma unroll
            for (int r = 0; r < 4; ++r) {
                int m = m0 + wr * 64 + mb * 16 + l4 * 4 + r;
                float val = acc[mb][nb][r] + bv;
                if (mode == 0) val *= SCLQ;  // fold softmax scale+log2e into Q
                if (mode == 3) {
                    ((float*)Cout)[(size_t)m * 512 + n] = val;
                } else {
                    int b = m >> 11, tok = m & 2047;
                    int h = n >> 6, d = n & 63;
                    short* o = (short*)Cout;
                    if (mode == 2)
                        o[((size_t)(b * 8 + h) * 64 + d) * 2048 + tok] = (short)f2bf(val);
                    else
                        o[((size_t)(b * 8 + h) * 2048 + tok) * 64 + d] = (short)f2bf(val);
                }
            }
        }
    }
}

// z-batched QKV projection: blockIdx.z selects {Q,K,V}
__global__ __launch_bounds__(256) void gemm_qkv_kernel(
    const short* __restrict__ Xq, const short* __restrict__ Xk, const short* __restrict__ Xv,
    const short* __restrict__ WqT, const short* __restrict__ WkT, const short* __restrict__ WvT,
    const float* __restrict__ bq, const float* __restrict__ bk, const float* __restrict__ bv,
    short* __restrict__ Qw, short* __restrict__ Kw, short* __restrict__ VTw)
{
    __shared__ char lds[32768];
    int z = blockIdx.z;
    const short* A = (z == 0) ? Xq : (z == 1) ? Xk : Xv;
    const short* BT = (z == 0) ? WqT : (z == 1) ? WkT : WvT;
    const float* bias = (z == 0) ? bq : (z == 1) ? bk : bv;
    void* Cout = (z == 0) ? (void*)Qw : (z == 1) ? (void*)Kw : (void*)VTw;
    gemm_body(A, BT, bias, Cout, z, lds, blockIdx.x, blockIdx.y);
}

__global__ __launch_bounds__(256) void gemm_kernel(
    const short* __restrict__ A, const short* __restrict__ BT,
    const float* __restrict__ bias, void* __restrict__ Cout, int mode)
{
    __shared__ char lds[32768];
    gemm_body(A, BT, bias, Cout, mode, lds, blockIdx.x, blockIdx.y);
}

// ---------------- masked flash attention: 8-wave, 16 q/wave, KVBLK=128 ----------------
// grid 512 = 8 XCD x 4 bh x 16 q-chunks of 128 (xcd = lid&7 pins bh to one XCD's L2).
// Per outer iteration: stage 128 tokens of K (2x8KB shots) and V (2x8KB shots) into
// a 16KB-per-operand double buffer, then run the R10-verified 64-token body TWICE
// (halves h=0,1), then ONE barrier. Halves use identical offsets +8192 (K) / +128B (V);
// swizzle keys unchanged since 64,32 are 0 mod 8. All fragment layouts, sigma16, mask
// C-init (bit ? -mrun : -1e30), deferred max merge (T13) verbatim R10.
__global__ __launch_bounds__(512) void attn_kernel(
    const short* __restrict__ Q, const short* __restrict__ K,
    const short* __restrict__ VT, const unsigned long long* __restrict__ mp,
    short* __restrict__ AO)
{
    __shared__ char lds[65536];  // K dbuf 2x16KB @0; V dbuf 2x16KB @32768
    const int tid = threadIdx.x;
    const int lane = tid & 63;
    const int wid = tid >> 6;
    const int l15 = lane & 15, l4 = lane >> 4;
    const int lid = blockIdx.x;
    const int xcd = lid & 7, jj = lid >> 3;
    const int bhi = (xcd << 2) | (jj >> 4);
    const int b = bhi >> 3, h = bhi & 7;
    const int q0 = (jj & 15) * 128 + wid * 16;
    const short* Qp = Q + ((size_t)bhi * 2048 + q0) * 64;
    const short* Kp = K + (size_t)bhi * 2048 * 64;
    const short* Vp = VT + (size_t)bhi * 64 * 2048;

    // staging maps (pre-swizzled global source; LDS dest linear = wavebase + lane*16)
    const int krow = tid >> 3;                       // K: row (token) 0..63 per shot
    const int kgo  = 8 * ((tid & 7) ^ (krow & 7));   // shot1 row=64+krow: same key (64%8=0)
    const int vrow0 = tid >> 4;                      // V: row (d) 0..31 shot0
    const int vgo   = 8 * ((tid & 15) ^ (vrow0 & 7)); // shot1 row=32+vrow0: same key
    const int vrow1 = 32 + vrow0;
    const int swl = l15 & 7;                         // read-side swizzle key (row & 7)

// stage K/V tile KT (128 tokens) into buffer BUF: 8 x global_load_lds w=16
#define STAGE(KT, BUF)                                                               \
    {                                                                                \
        const short* Kn = Kp + (size_t)(KT) * 128 * 64;                              \
        char* Kd = lds + (BUF) * 16384;                                              \
        GLOAD_LDS16(Kn + (size_t)krow * 64 + kgo, Kd + wid * 1024);                  \
        GLOAD_LDS16(Kn + (size_t)(64 + krow) * 64 + kgo, Kd + 8192 + wid * 1024);    \
        const short* Vn = Vp + (KT) * 128;                                           \
        char* Vd = lds + 32768 + (BUF) * 16384;                                      \
        GLOAD_LDS16(Vn + (size_t)vrow0 * 2048 + vgo, Vd + wid * 1024);               \
        GLOAD_LDS16(Vn + (size_t)vrow1 * 2048 + vgo, Vd + 8192 + wid * 1024);        \
    }

    // Q B-frags: qb[dc] = Q[q0+l15][dc*32+l4*8+j]
    bf16x8 qb[2];
#pragma unroll
    for (int dc = 0; dc < 2; ++dc)
        qb[dc] = *(const bf16x8*)(Qp + l15 * 64 + dc * 32 + l4 * 8);

    f32x4 o[4];  // o[dt]: q = l4*4 + r, d = dt*16 + l15
#pragma unroll
    for (int dt = 0; dt < 4; ++dt) o[dt] = f32x4{0.f, 0.f, 0.f, 0.f};
    float mrun = 0.f, lrun = 0.f;  // R10 semantics: violation raises mrun if needed

    const unsigned long long* mr0 = mp + ((size_t)b * 2048 + q0 + l15) * 32;

    STAGE(0, 0)
    ulonglong2 mwv = *(const ulonglong2*)(mr0);   // words for tile 0 (halves 0,1)
    __syncthreads();

// one 64-token half: R10-verified body. H = 0/1 selects LDS sub-tile; MW = mask word.
#define HALF(H, MW)                                                                  \
    {                                                                                \
        bf16x8 ka[4][2];                                                             \
        _Pragma("unroll") for (int tb = 0; tb < 4; ++tb)                             \
            _Pragma("unroll") for (int dc = 0; dc < 2; ++dc)                         \
                ka[tb][dc] = *(const bf16x8*)(Kc + (H) * 8192 +                      \
                                              (tb * 16 + l15) * 128 +                \
                                              16 * ((dc * 4 + l4) ^ swl));           \
        bf16x8 vb[4][2];                                                             \
        _Pragma("unroll") for (int dt = 0; dt < 4; ++dt)                             \
            _Pragma("unroll") for (int kb = 0; kb < 2; ++kb) {                       \
                const char* vr = Vc + (dt * 16 + l15) * 256;                         \
                uint2 x = *(const uint2*)(vr +                                       \
                    16 * (((H) * 8 + kb * 4 + (l4 >> 1)) ^ swl) + (l4 & 1) * 8);     \
                uint2 y = *(const uint2*)(vr +                                       \
                    16 * (((H) * 8 + kb * 4 + 2 + (l4 >> 1)) ^ swl) + (l4 & 1) * 8); \
                uint4 t; t.x = x.x; t.y = x.y; t.z = y.x; t.w = y.y;                 \
                vb[dt][kb] = *(bf16x8*)&t;                                           \
            }                                                                        \
        const float nm = -mrun;                                                      \
        unsigned long long u64 = (MW) >> (l4 * 4);                                   \
        unsigned ulo = (unsigned)u64, uhi = (unsigned)(u64 >> 32);                   \
        f32x4 sv[4];                                                                 \
        _Pragma("unroll") for (int tb = 0; tb < 4; ++tb) {                           \
            unsigned us = (tb & 2) ? uhi : ulo;                                      \
            f32x4 i0;                                                                \
            _Pragma("unroll") for (int r = 0; r < 4; ++r)                            \
                i0[r] = (us & (1u << (((tb & 1) << 4) + r))) ? nm : -1e30f;          \
            sv[tb] = mfma16(ka[tb][1], qb[1], mfma16(ka[tb][0], qb[0], i0));         \
        }                                                                            \
        float pml;                                                                   \
        {                                                                            \
            f32x4 m0v;                                                               \
            _Pragma("unroll") for (int r = 0; r < 4; ++r)                            \
                m0v[r] = fmaxf(fmaxf(sv[0][r], sv[1][r]), fmaxf(sv[2][r], sv[3][r]));\
            pml = fmaxf(fmaxf(m0v[0], m0v[1]), fmaxf(m0v[2], m0v[3]));               \
        }                                                                            \
        if (__any(pml > 8.f)) {                                                      \
            float pm = fmaxf(pml, __shfl_xor(pml, 16, 64));                          \
            pm = fmaxf(pm, __shfl_xor(pm, 32, 64));                                  \
            float dm = fmaxf(pm, 0.f);                                               \
            float al = exp2f(-dm);                                                   \
            mrun += dm;                                                              \
            lrun *= al;                                                              \
            _Pragma("unroll") for (int r = 0; r < 4; ++r) {                          \
                float alr = __shfl(al, l4 * 4 + r, 64);                              \
                _Pragma("unroll") for (int dt = 0; dt < 4; ++dt) o[dt][r] *= alr;    \
            }                                                                        \
            _Pragma("unroll") for (int tb = 0; tb < 4; ++tb)                         \
                _Pragma("unroll") for (int r = 0; r < 4; ++r) sv[tb][r] -= dm;       \
        }                                                                            \
        _Pragma("unroll") for (int tb = 0; tb < 4; ++tb)                             \
            _Pragma("unroll") for (int r = 0; r < 4; ++r)                            \
                sv[tb][r] = exp2f(sv[tb][r]);                                        \
        {                                                                            \
            f32x4 t0 = (sv[0] + sv[1]) + (sv[2] + sv[3]);                            \
            lrun += (t0[0] + t0[1]) + (t0[2] + t0[3]);                               \
        }                                                                            \
        bf16x8 pa[2];                                                                \
        {                                                                            \
            uint4 t_;                                                                \
            asm("v_cvt_pk_bf16_f32 %0, %1, %2" : "=v"(t_.x) : "v"(sv[0][0]), "v"(sv[0][1])); \
            asm("v_cvt_pk_bf16_f32 %0, %1, %2" : "=v"(t_.y) : "v"(sv[0][2]), "v"(sv[0][3])); \
            asm("v_cvt_pk_bf16_f32 %0, %1, %2" : "=v"(t_.z) : "v"(sv[1][0]), "v"(sv[1][1])); \
            asm("v_cvt_pk_bf16_f32 %0, %1, %2" : "=v"(t_.w) : "v"(sv[1][2]), "v"(sv[1][3])); \
            pa[0] = *(bf16x8*)&t_;                                                   \
            asm("v_cvt_pk_bf16_f32 %0, %1, %2" : "=v"(t_.x) : "v"(sv[2][0]), "v"(sv[2][1])); \
            asm("v_cvt_pk_bf16_f32 %0, %1, %2" : "=v"(t_.y) : "v"(sv[2][2]), "v"(sv[2][3])); \
            asm("v_cvt_pk_bf16_f32 %0, %1, %2" : "=v"(t_.z) : "v"(sv[3][0]), "v"(sv[3][1])); \
            asm("v_cvt_pk_bf16_f32 %0, %1, %2" : "=v"(t_.w) : "v"(sv[3][2]), "v"(sv[3][3])); \
            pa[1] = *(bf16x8*)&t_;                                                   \
        }                                                                            \
        _Pragma("unroll") for (int dt = 0; dt < 4; ++dt)                             \
            o[dt] = mfma16(pa[1], vb[dt][1], mfma16(pa[0], vb[dt][0], o[dt]));       \
    }

    for (int kt = 0; kt < 16; ++kt) {
        const int cur = kt & 1;
        char* Kc = lds + cur * 16384;
        char* Vc = lds + 32768 + cur * 16384;
        if (kt < 15) STAGE(kt + 1, cur ^ 1)
        ulonglong2 mwn;
        mwn.x = 0; mwn.y = 0;
        if (kt < 15) mwn = *(const ulonglong2*)(mr0 + 2 * kt + 2);
        HALF(0, mwv.x)
        HALF(1, mwv.y)
        mwv = mwn;
        __syncthreads();  // drains next-tile staging + all LDS reads; swap buffers
    }
#undef HALF
#undef STAGE

    // epilogue: merge l4-group partial sums, normalize, store
    {
        float lt = lrun;
        lt += __shfl_xor(lt, 16, 64);
        lt += __shfl_xor(lt, 32, 64);
        float inv = 1.0f / lt;  // for q = q0 + l15
#pragma unroll
        for (int r = 0; r < 4; ++r) {
            float invr = __shfl(inv, l4 * 4 + r, 64);
            size_t base = ((size_t)b * 2048 + q0 + l4 * 4 + r) * 512 + h * 64;
#pragma unroll
            for (int dt = 0; dt < 4; ++dt)
                AO[base + dt * 16 + l15] = (short)f2bf(o[dt][r] * invr);
        }
    }
}

// ---------------- launcher ----------------
extern "C" void kernel_launch(void* const* d_in, const int* in_sizes, int n_in,
                              void* d_out, int out_size, void* d_ws, size_t ws_size,
                              hipStream_t stream) {
    const float* q  = (const float*)d_in[0];
    const float* k  = (const float*)d_in[1];
    const float* v  = (const float*)d_in[2];
    const int*   gm = (const int*)d_in[3];
    const float* Wq = (const float*)d_in[4];  const float* bq = (const float*)d_in[5];
    const float* Wk = (const float*)d_in[6];  const float* bk = (const float*)d_in[7];
    const float* Wv = (const float*)d_in[8];  const float* bv = (const float*)d_in[9];
    const float* Wo = (const float*)d_in[10]; const float* bo = (const float*)d_in[11];

    char* ws = (char*)d_ws;
    short* Xq  = (short*)(ws + 0);
    short* Xk  = (short*)(ws + 8388608);
    short* Xv  = (short*)(ws + 16777216);
    short* WqT = (short*)(ws + 25165824);
    short* WkT = (short*)(ws + 25690112);
    short* WvT = (short*)(ws + 26214400);
    short* WoT = (short*)(ws + 26738688);
    short* Qw  = (short*)(ws + 27262976);    // [b,h,tok,d] (pre-scaled)
    short* Kw  = (short*)(ws + 35651584);    // [b,h,tok,d]
    short* VTw = (short*)(ws + 44040192);    // [b,h,d,tok]
    short* AO  = (short*)(ws + 52428800);    // attn out [b,tok,h*64+d]
    unsigned long long* MP = (unsigned long long*)(ws + 60817408);

    cvt_x_kernel<<<dim3(4096, 3), 256, 0, stream>>>(q, k, v, Xq, Xk, Xv);
    cvt_wt_kernel<<<dim3(128, 4), 256, 0, stream>>>(Wq, Wk, Wv, Wo, WqT, WkT, WvT, WoT);
    pack_mask_kernel<<<dim3(2048), 256, 0, stream>>>(gm, MP);

    gemm_qkv_kernel<<<dim3(4, 64, 3), 256, 0, stream>>>(Xq, Xk, Xv, WqT, WkT, WvT,
                                                        bq, bk, bv, Qw, Kw, VTw);

    attn_kernel<<<dim3(512), 512, 0, stream>>>(Qw, Kw, VTw, MP, AO);

    gemm_kernel<<<dim3(4, 64), 256, 0, stream>>>(AO, WoT, bo, (void*)d_out, 3);
}